// Round 2
// baseline (3473.575 us; speedup 1.0000x reference)
//
#include <hip/hip_runtime.h>

// NeuronInteraction: B=32, N=4096, D=256, H=4, hd=64, MSG_K=256, k=256
// Pipeline:
//  fill0 -> topk1(sort acts) -> convW(bf16 weights) -> gatherX(bf16 candidate rows)
//  -> fp32 attention chain (qkv, scores, softmax, PV, MSG, MSGC)
//  -> bf16 MFMA MLPs: su1 (gelu) -> su2 (+LN) -> au (gelu.dot+sigmoid)
//  -> selectT (rank-256 value) -> bandfix (fp32 recompute of |na-T|<eps rows)
//  -> topk2 (sort candidates) -> scatter.
// Candidate pruning: rows with a < a*(256th) - 3/7 provably can't be selected.

constexpr int KC = 32;
constexpr int CMAX = 2304;           // E[cands]=2012, sigma~32 -> +9 sigma
constexpr float BAND_EPS = 0.01f;    // ~100x bf16-path na error bound

typedef short bf16x8 __attribute__((ext_vector_type(8)));
typedef float f32x4 __attribute__((ext_vector_type(4)));

__device__ __forceinline__ float gelu_f(float x) {
    return 0.5f * x * (1.0f + erff(x * 0.70710678118654752440f));
}
__device__ __forceinline__ unsigned short f2bf(float f) {
    unsigned u = __float_as_uint(f);
    return (unsigned short)((u + 0x7fffu + ((u >> 16) & 1u)) >> 16);
}
__device__ __forceinline__ float bf2f(unsigned short h) {
    return __uint_as_float(((unsigned)h) << 16);
}

// ---------------- zero-fill output ----------------
__global__ void __launch_bounds__(256) fill0_k(float4* p, long n4) {
    long i = (long)blockIdx.x * 256 + threadIdx.x;
    long stride = (long)gridDim.x * 256;
    float4 z = make_float4(0.f, 0.f, 0.f, 0.f);
    for (; i < n4; i += stride) p[i] = z;
}

// ---------------- top-k #1: full descending sort of activations ----------------
__global__ void __launch_bounds__(256) topk1_k(const float* __restrict__ act,
        float* __restrict__ svals, int* __restrict__ sidx, int* __restrict__ cnt)
{
    __shared__ unsigned long long keys[4096];
    int b = blockIdx.x, tid = threadIdx.x;
    for (int s = 0; s < 16; ++s) {
        int i = s * 256 + tid;
        unsigned vb = __float_as_uint(act[b * 4096 + i]);
        keys[i] = ((unsigned long long)vb << 32) | (unsigned)(~i);
    }
    __syncthreads();
    for (int k = 2; k <= 4096; k <<= 1) {
        for (int j = k >> 1; j > 0; j >>= 1) {
            for (int s = 0; s < 16; ++s) {
                int i = s * 256 + tid;
                int l = i ^ j;
                if (l > i) {
                    unsigned long long a = keys[i], c = keys[l];
                    bool sw = ((i & k) == 0) ? (a < c) : (a > c); // descending
                    if (sw) { keys[i] = c; keys[l] = a; }
                }
            }
            __syncthreads();
        }
    }
    float th = __uint_as_float((unsigned)(keys[255] >> 32)) - 0.4288f; // > 3/7 margin
    for (int s = 0; s < 16; ++s) {
        int i = s * 256 + tid;
        unsigned long long key = keys[i];
        float v = __uint_as_float((unsigned)(key >> 32));
        svals[b * 4096 + i] = v;
        sidx[b * 4096 + i] = (int)(~(unsigned)key);
        if (v >= th) {
            bool nxt = (i == 4095) ? false
                     : (__uint_as_float((unsigned)(keys[i + 1] >> 32)) >= th);
            if (!nxt) cnt[b] = (i + 1 < CMAX) ? (i + 1) : CMAX;
        }
    }
}

// ---------------- top-k #2: sort candidates by new activation ----------------
__global__ void __launch_bounds__(256) topk2_k(const float* __restrict__ newact,
        const int* __restrict__ sidx, const int* __restrict__ cnt,
        float* __restrict__ selv, int* __restrict__ selo, int* __restrict__ selp)
{
    __shared__ unsigned long long keys[4096];
    __shared__ unsigned short pay[4096];
    int b = blockIdx.x, tid = threadIdx.x;
    int C = min(cnt[b], CMAX);
    for (int s = 0; s < 16; ++s) {
        int i = s * 256 + tid;
        unsigned long long key = 0ull;
        if (i < C) {
            unsigned vb = __float_as_uint(newact[(long)b * CMAX + i]);
            unsigned orig = (unsigned)sidx[b * 4096 + i];
            key = ((unsigned long long)vb << 32) | (unsigned)(~orig);
        }
        keys[i] = key; pay[i] = (unsigned short)i;
    }
    __syncthreads();
    for (int k = 2; k <= 4096; k <<= 1) {
        for (int j = k >> 1; j > 0; j >>= 1) {
            for (int s = 0; s < 16; ++s) {
                int i = s * 256 + tid;
                int l = i ^ j;
                if (l > i) {
                    unsigned long long a = keys[i], c = keys[l];
                    bool sw = ((i & k) == 0) ? (a < c) : (a > c);
                    if (sw) {
                        keys[i] = c; keys[l] = a;
                        unsigned short t = pay[i]; pay[i] = pay[l]; pay[l] = t;
                    }
                }
            }
            __syncthreads();
        }
    }
    unsigned long long key = keys[tid];
    selv[b * 256 + tid] = __uint_as_float((unsigned)(key >> 32));
    selo[b * 256 + tid] = (int)(~(unsigned)key);
    selp[b * 256 + tid] = (int)pay[tid];
}

// ---------------- generic fp32 tiled GEMM (attention chain) ----------------
// EPI: 0 none, 1 +bias[n], 2 (+bias[n])*rowscale[m], 3 *cscale
template<int TM, int TN, int RM, int RN, bool BT, bool GATHER, int EPI>
__global__ void __launch_bounds__(256) gemm_k(
    const float* __restrict__ A, int lda, long sA1, long sA2, int divA,
    const float* __restrict__ B, int ldb, long sB1, long sB2, int divB,
    float* __restrict__ C, int ldc, long sC1, long sC2, int divC,
    int K, const float* __restrict__ bias, const float* __restrict__ rowscale,
    long rsStride, const int* __restrict__ gmap, long gmapStride, float cscale)
{
    constexpr int TX = TN / RN, TY = TM / RM;
    static_assert(TX * TY == 256, "block must be 256 threads");
    __shared__ float As[KC][TM + 4];
    __shared__ float Bs[KC][TN + 4];
    int z = blockIdx.z;
    const float* Ab = A + (long)(z / divA) * sA1 + (long)(z % divA) * sA2;
    const float* Bb = B + (long)(z / divB) * sB1 + (long)(z % divB) * sB2;
    float* Cb = C + (long)(z / divC) * sC1 + (long)(z % divC) * sC2;
    int m0 = blockIdx.y * TM, n0 = blockIdx.x * TN;
    int tid = threadIdx.x;
    int tx = tid % TX, ty = tid / TX;
    float acc[RM][RN];
    #pragma unroll
    for (int i = 0; i < RM; ++i)
        #pragma unroll
        for (int j = 0; j < RN; ++j) acc[i][j] = 0.f;

    for (int k0 = 0; k0 < K; k0 += KC) {
        __syncthreads();
        #pragma unroll
        for (int u = 0; u < (TM * KC) / 1024; ++u) {
            int idx = tid + u * 256;
            int m = idx / (KC / 4), k4 = idx % (KC / 4);
            int row = m0 + m;
            long grow = GATHER ? (long)gmap[(long)z * gmapStride + row] : (long)row;
            float4 v = *(const float4*)(Ab + grow * lda + k0 + k4 * 4);
            As[k4 * 4 + 0][m] = v.x; As[k4 * 4 + 1][m] = v.y;
            As[k4 * 4 + 2][m] = v.z; As[k4 * 4 + 3][m] = v.w;
        }
        if (BT) {
            #pragma unroll
            for (int u = 0; u < (TN * KC) / 1024; ++u) {
                int idx = tid + u * 256;
                int n = idx / (KC / 4), k4 = idx % (KC / 4);
                float4 v = *(const float4*)(Bb + (long)(n0 + n) * ldb + k0 + k4 * 4);
                Bs[k4 * 4 + 0][n] = v.x; Bs[k4 * 4 + 1][n] = v.y;
                Bs[k4 * 4 + 2][n] = v.z; Bs[k4 * 4 + 3][n] = v.w;
            }
        } else {
            #pragma unroll
            for (int u = 0; u < (TN * KC) / 1024; ++u) {
                int idx = tid + u * 256;
                int k = idx / (TN / 4), n4 = idx % (TN / 4);
                float4 v = *(const float4*)(Bb + (long)(k0 + k) * ldb + n0 + n4 * 4);
                *(float4*)&Bs[k][n4 * 4] = v;
            }
        }
        __syncthreads();
        #pragma unroll
        for (int k = 0; k < KC; ++k) {
            float av[RM], bv[RN];
            #pragma unroll
            for (int i = 0; i < RM; i += 4) {
                float4 t = *(const float4*)&As[k][ty * RM + i];
                av[i] = t.x; av[i + 1] = t.y; av[i + 2] = t.z; av[i + 3] = t.w;
            }
            #pragma unroll
            for (int j = 0; j < RN; j += 4) {
                float4 t = *(const float4*)&Bs[k][tx * RN + j];
                bv[j] = t.x; bv[j + 1] = t.y; bv[j + 2] = t.z; bv[j + 3] = t.w;
            }
            #pragma unroll
            for (int i = 0; i < RM; ++i)
                #pragma unroll
                for (int j = 0; j < RN; ++j)
                    acc[i][j] = fmaf(av[i], bv[j], acc[i][j]);
        }
    }
    #pragma unroll
    for (int i = 0; i < RM; ++i) {
        int gm = m0 + ty * RM + i;
        float rs = 1.f;
        if (EPI == 2) rs = rowscale[(long)z * rsStride + gm];
        #pragma unroll
        for (int j = 0; j < RN; j += 4) {
            int gn = n0 + tx * RN + j;
            float4 v = make_float4(acc[i][j], acc[i][j + 1], acc[i][j + 2], acc[i][j + 3]);
            if (EPI == 1 || EPI == 2) {
                float4 bb = *(const float4*)(bias + gn);
                v.x += bb.x; v.y += bb.y; v.z += bb.z; v.w += bb.w;
            }
            if (EPI == 2) { v.x *= rs; v.y *= rs; v.z *= rs; v.w *= rs; }
            if (EPI == 3) { v.x *= cscale; v.y *= cscale; v.z *= cscale; v.w *= cscale; }
            *(float4*)(Cb + (long)gm * ldc + gn) = v;
        }
    }
}

// ---------------- softmax over rows of 256 (1 wave / row) ----------------
__global__ void __launch_bounds__(256) softmax_k(float* __restrict__ S) {
    int row = blockIdx.x * 4 + (threadIdx.x >> 6);
    int lane = threadIdx.x & 63;
    float4* r = (float4*)(S + (long)row * 256);
    float4 v = r[lane];
    float m = fmaxf(fmaxf(v.x, v.y), fmaxf(v.z, v.w));
    for (int off = 32; off >= 1; off >>= 1) m = fmaxf(m, __shfl_xor(m, off));
    v.x = expf(v.x - m); v.y = expf(v.y - m); v.z = expf(v.z - m); v.w = expf(v.w - m);
    float s = v.x + v.y + v.z + v.w;
    for (int off = 32; off >= 1; off >>= 1) s += __shfl_xor(s, off);
    float inv = 1.f / s;
    v.x *= inv; v.y *= inv; v.z *= inv; v.w *= inv;
    r[lane] = v;
}

// ---------------- weight fp32->bf16 conversion ----------------
__global__ void __launch_bounds__(256) convw_k(
        const float* __restrict__ s1, const float* __restrict__ s2,
        const float* __restrict__ a1,
        unsigned short* __restrict__ o1, unsigned short* __restrict__ o2,
        unsigned short* __restrict__ o3)
{
    int i = blockIdx.x * 256 + threadIdx.x;   // grid 512 -> 131072
    o1[i] = f2bf(s1[i]);
    o3[i] = f2bf(a1[i]);
    if (i < 65536) o2[i] = f2bf(s2[i]);
}

// ---------------- gather candidate rows -> bf16 [B][CMAX][256] ----------------
__global__ void __launch_bounds__(256) gatherX_k(const float* __restrict__ hid,
        const int* __restrict__ sidx, const int* __restrict__ cnt,
        unsigned short* __restrict__ Xb)
{
    int b = blockIdx.y;
    int C = min(cnt[b], CMAX);
    int p = blockIdx.x * 4 + (threadIdx.x >> 6);
    int lane = threadIdx.x & 63;
    unsigned short* dst = Xb + ((long)b * CMAX + p) * 256 + lane * 4;
    if (p < C) {
        int row = sidx[b * 4096 + p];
        float4 v = *(const float4*)(hid + ((long)b * 4096 + row) * 256 + lane * 4);
        ushort4 o; o.x = f2bf(v.x); o.y = f2bf(v.y); o.z = f2bf(v.z); o.w = f2bf(v.w);
        *(ushort4*)dst = o;
    } else {
        ushort4 z; z.x = 0; z.y = 0; z.z = 0; z.w = 0;
        *(ushort4*)dst = z;
    }
}

// ---------------- bf16 MFMA MLP: block = 64 rows x 256 cols, 4 waves 1x4 ----
// STAGE 1: H1b = bf16(gelu(Xb@W1a^T + b1 + msgc))
// STAGE 2: NHb = bf16(LN(H1b@W2^T + b2))
// STAGE 3: nac = clip(0.7a + 0.3 sigmoid(gelu([Xb,NHb]@auW1^T + b1).w2 + b2))
template<int STAGE>
__global__ void __launch_bounds__(256, 2) mlp_mfma_k(
    const unsigned short* __restrict__ A0,
    const unsigned short* __restrict__ A1,
    const unsigned short* __restrict__ W, int ldw,
    const float* __restrict__ bias,
    const float* __restrict__ msgc,
    const float* __restrict__ lng, const float* __restrict__ lnb,
    const float* __restrict__ w2v, const float* __restrict__ b2s,
    const float* __restrict__ svals,
    const int* __restrict__ cnt,
    unsigned short* __restrict__ outb,
    float* __restrict__ nac)
{
    int b = blockIdx.y;
    int C = min(cnt[b], CMAX);
    int m0 = blockIdx.x * 64;
    if (m0 >= C) return;
    int tid = threadIdx.x;
    int wid = tid >> 6;
    int lane = tid & 63;
    int l15 = lane & 15;
    int q = lane >> 4;
    int n0w = wid * 64;

    f32x4 acc[4][4];
    #pragma unroll
    for (int mt = 0; mt < 4; ++mt)
        #pragma unroll
        for (int nt = 0; nt < 4; ++nt) {
            f32x4 z = {0.f, 0.f, 0.f, 0.f};
            acc[mt][nt] = z;
        }

    const unsigned short* Ab = A0 + ((long)b * CMAX + m0) * 256;
    const unsigned short* A1b = (STAGE == 3) ? (A1 + ((long)b * CMAX + m0) * 256) : nullptr;
    int aoff[4];
    #pragma unroll
    for (int mt = 0; mt < 4; ++mt) aoff[mt] = (mt * 16 + l15) * 256;
    const unsigned short* wr[4];
    #pragma unroll
    for (int nt = 0; nt < 4; ++nt) wr[nt] = W + (long)(n0w + nt * 16 + l15) * ldw;

    constexpr int KSTEPS = (STAGE == 3) ? 16 : 8;
    #pragma unroll 4
    for (int ks = 0; ks < KSTEPS; ++ks) {
        const unsigned short* As = (STAGE == 3 && ks >= 8) ? A1b : Ab;
        int ko = (STAGE == 3 && ks >= 8) ? (ks - 8) * 32 : ks * 32;
        int kw = ks * 32;
        bf16x8 af[4], bfr[4];
        #pragma unroll
        for (int mt = 0; mt < 4; ++mt)
            af[mt] = *(const bf16x8*)(As + aoff[mt] + ko + q * 8);
        #pragma unroll
        for (int nt = 0; nt < 4; ++nt)
            bfr[nt] = *(const bf16x8*)(wr[nt] + kw + q * 8);
        #pragma unroll
        for (int mt = 0; mt < 4; ++mt)
            #pragma unroll
            for (int nt = 0; nt < 4; ++nt)
                acc[mt][nt] = __builtin_amdgcn_mfma_f32_16x16x32_bf16(
                    af[mt], bfr[nt], acc[mt][nt], 0, 0, 0);
    }

    if constexpr (STAGE == 1) {
        float bb[4];
        #pragma unroll
        for (int nt = 0; nt < 4; ++nt) bb[nt] = bias[n0w + nt * 16 + l15];
        #pragma unroll
        for (int mt = 0; mt < 4; ++mt) {
            #pragma unroll
            for (int reg = 0; reg < 4; ++reg) {
                int p = m0 + mt * 16 + q * 4 + reg;
                long orow = ((long)b * CMAX + p) * 256;
                const float* mrow = msgc + ((long)b * 256 + p) * 256;
                bool hasm = (p < 256);
                #pragma unroll
                for (int nt = 0; nt < 4; ++nt) {
                    int gc = n0w + nt * 16 + l15;
                    float v = acc[mt][nt][reg] + bb[nt];
                    if (hasm) v += mrow[gc];
                    outb[orow + gc] = f2bf(gelu_f(v));
                }
            }
        }
    }

    if constexpr (STAGE == 2) {
        __shared__ float rsum[4][64];
        __shared__ float rsq[4][64];
        __shared__ float rmu[64], rrs[64];
        float bb[4], gg[4], eb[4];
        #pragma unroll
        for (int nt = 0; nt < 4; ++nt) {
            int gc = n0w + nt * 16 + l15;
            bb[nt] = bias[gc]; gg[nt] = lng[gc]; eb[nt] = lnb[gc];
        }
        #pragma unroll
        for (int mt = 0; mt < 4; ++mt)
            #pragma unroll
            for (int nt = 0; nt < 4; ++nt)
                #pragma unroll
                for (int reg = 0; reg < 4; ++reg)
                    acc[mt][nt][reg] += bb[nt];
        #pragma unroll
        for (int mt = 0; mt < 4; ++mt) {
            #pragma unroll
            for (int reg = 0; reg < 4; ++reg) {
                float s = 0.f, s2 = 0.f;
                #pragma unroll
                for (int nt = 0; nt < 4; ++nt) {
                    float v = acc[mt][nt][reg];
                    s += v; s2 += v * v;
                }
                #pragma unroll
                for (int off = 1; off <= 8; off <<= 1) {
                    s += __shfl_xor(s, off);
                    s2 += __shfl_xor(s2, off);
                }
                if (l15 == 0) {
                    int row = mt * 16 + q * 4 + reg;
                    rsum[wid][row] = s; rsq[wid][row] = s2;
                }
            }
        }
        __syncthreads();
        if (tid < 64) {
            float s = rsum[0][tid] + rsum[1][tid] + rsum[2][tid] + rsum[3][tid];
            float s2 = rsq[0][tid] + rsq[1][tid] + rsq[2][tid] + rsq[3][tid];
            float mu = s * (1.f / 256.f);
            float var = s2 * (1.f / 256.f) - mu * mu;
            rmu[tid] = mu;
            rrs[tid] = rsqrtf(var + 1e-5f);
        }
        __syncthreads();
        #pragma unroll
        for (int mt = 0; mt < 4; ++mt) {
            #pragma unroll
            for (int reg = 0; reg < 4; ++reg) {
                int row = mt * 16 + q * 4 + reg;
                int p = m0 + row;
                float mu = rmu[row], rs = rrs[row];
                long orow = ((long)b * CMAX + p) * 256;
                #pragma unroll
                for (int nt = 0; nt < 4; ++nt) {
                    int gc = n0w + nt * 16 + l15;
                    outb[orow + gc] = f2bf((acc[mt][nt][reg] - mu) * rs * gg[nt] + eb[nt]);
                }
            }
        }
    }

    if constexpr (STAGE == 3) {
        __shared__ float rsum[4][64];
        float bb[4], ww[4];
        #pragma unroll
        for (int nt = 0; nt < 4; ++nt) {
            int gc = n0w + nt * 16 + l15;
            bb[nt] = bias[gc]; ww[nt] = w2v[gc];
        }
        #pragma unroll
        for (int mt = 0; mt < 4; ++mt) {
            #pragma unroll
            for (int reg = 0; reg < 4; ++reg) {
                float s = 0.f;
                #pragma unroll
                for (int nt = 0; nt < 4; ++nt)
                    s += gelu_f(acc[mt][nt][reg] + bb[nt]) * ww[nt];
                #pragma unroll
                for (int off = 1; off <= 8; off <<= 1) s += __shfl_xor(s, off);
                if (l15 == 0) rsum[wid][mt * 16 + q * 4 + reg] = s;
            }
        }
        __syncthreads();
        if (tid < 64) {
            int p = m0 + tid;
            if (p < C) {
                float z = rsum[0][tid] + rsum[1][tid] + rsum[2][tid] + rsum[3][tid] + b2s[0];
                float delta = 1.f / (1.f + expf(-z));
                float na = 0.7f * svals[b * 4096 + p] + 0.3f * delta;
                nac[(long)b * CMAX + p] = fminf(fmaxf(na, 0.f), 1.f);
            }
        }
    }
}

// ---------------- rank-256 value via bit/value binary search ----------------
__global__ void __launch_bounds__(256) selectT_k(const float* __restrict__ nac,
        const int* __restrict__ cnt, float* __restrict__ T)
{
    __shared__ float v[CMAX];
    __shared__ int cs[256];
    __shared__ float bounds[2];
    int b = blockIdx.x, tid = threadIdx.x;
    int C = min(cnt[b], CMAX);
    for (int i = tid; i < CMAX; i += 256)
        v[i] = (i < C) ? nac[(long)b * CMAX + i] : -1.f;
    if (tid == 0) { bounds[0] = 0.f; bounds[1] = 1.0f; }
    __syncthreads();
    for (int it = 0; it < 30; ++it) {
        float mid = 0.5f * (bounds[0] + bounds[1]);
        int c = 0;
        for (int i = tid; i < CMAX; i += 256) c += (v[i] >= mid) ? 1 : 0;
        cs[tid] = c; __syncthreads();
        for (int s = 128; s; s >>= 1) {
            if (tid < s) cs[tid] += cs[tid + s];
            __syncthreads();
        }
        if (tid == 0) { if (cs[0] >= 256) bounds[0] = mid; else bounds[1] = mid; }
        __syncthreads();
    }
    if (tid == 0) T[b] = bounds[0];
}

__device__ __forceinline__ float blk_reduce(float x, float* red, int tid) {
    red[tid] = x; __syncthreads();
    for (int s = 128; s; s >>= 1) {
        if (tid < s) red[tid] += red[tid + s];
        __syncthreads();
    }
    float r = red[0]; __syncthreads();
    return r;
}

// ---------------- fp32 recompute for rows near the selection boundary --------
__global__ void __launch_bounds__(256) bandfix_k(
    const float* __restrict__ hid, const int* __restrict__ sidx,
    const int* __restrict__ cnt, const float* __restrict__ msgc,
    const float* __restrict__ su_w1, const float* __restrict__ su_b1,
    const float* __restrict__ su_w2, const float* __restrict__ su_b2,
    const float* __restrict__ ln_g, const float* __restrict__ ln_b,
    const float* __restrict__ au_w1, const float* __restrict__ au_b1,
    const float* __restrict__ au_w2, const float* __restrict__ au_b2,
    const float* __restrict__ svals, const float* __restrict__ Tarr,
    float* __restrict__ nac, unsigned short* __restrict__ NHb)
{
    int b = blockIdx.y;
    int C = min(cnt[b], CMAX);
    int base = blockIdx.x * 256;
    int tid = threadIdx.x;
    __shared__ int list[256];
    __shared__ int nl;
    if (tid == 0) nl = 0;
    __syncthreads();
    int p = base + tid;
    if (p < C && fabsf(nac[(long)b * CMAX + p] - Tarr[b]) < BAND_EPS) {
        list[atomicAdd(&nl, 1)] = p;
    }
    __syncthreads();
    int M = nl;
    __shared__ float xr[256], h1[256], nh[256], red[256];
    for (int li = 0; li < M; ++li) {
        int pp = list[li];
        int row = sidx[b * 4096 + pp];
        int n = tid;
        xr[n] = hid[((long)b * 4096 + row) * 256 + n];
        __syncthreads();
        // su stage 1
        float s = su_b1[n];
        if (pp < 256) s += msgc[((long)b * 256 + pp) * 256 + n];
        {
            const float* w = su_w1 + (long)n * 512;
            #pragma unroll 4
            for (int k = 0; k < 256; k += 4) {
                float4 wv = *(const float4*)(w + k);
                s += xr[k] * wv.x + xr[k + 1] * wv.y + xr[k + 2] * wv.z + xr[k + 3] * wv.w;
            }
        }
        float h = gelu_f(s);
        h1[n] = h;
        __syncthreads();
        // su stage 2 + LN
        float y = su_b2[n];
        {
            const float* w = su_w2 + (long)n * 256;
            #pragma unroll 4
            for (int k = 0; k < 256; k += 4) {
                float4 wv = *(const float4*)(w + k);
                y += h1[k] * wv.x + h1[k + 1] * wv.y + h1[k + 2] * wv.z + h1[k + 3] * wv.w;
            }
        }
        float mu = blk_reduce(y, red, tid) * (1.f / 256.f);
        float d = y - mu;
        float var = blk_reduce(d * d, red, tid) * (1.f / 256.f);
        float o = d * rsqrtf(var + 1e-5f) * ln_g[n] + ln_b[n];
        nh[n] = o;
        NHb[((long)b * CMAX + pp) * 256 + n] = f2bf(o);
        __syncthreads();
        // au
        float ax = au_b1[n];
        {
            const float* w = au_w1 + (long)n * 512;
            #pragma unroll 4
            for (int k = 0; k < 256; k += 4) {
                float4 wv = *(const float4*)(w + k);
                ax += xr[k] * wv.x + xr[k + 1] * wv.y + xr[k + 2] * wv.z + xr[k + 3] * wv.w;
            }
            const float* w2 = w + 256;
            #pragma unroll 4
            for (int k = 0; k < 256; k += 4) {
                float4 wv = *(const float4*)(w2 + k);
                ax += nh[k] * wv.x + nh[k + 1] * wv.y + nh[k + 2] * wv.z + nh[k + 3] * wv.w;
            }
        }
        float z = blk_reduce(gelu_f(ax) * au_w2[n], red, tid) + au_b2[0];
        if (tid == 0) {
            float delta = 1.f / (1.f + expf(-z));
            float na = 0.7f * svals[b * 4096 + pp] + 0.3f * delta;
            nac[(long)b * CMAX + pp] = fminf(fmaxf(na, 0.f), 1.f);
        }
        __syncthreads();
    }
}

// ---------------- scatter outputs ----------------
__global__ void __launch_bounds__(64) scatter_k(const float* __restrict__ selv,
        const int* __restrict__ selo, const int* __restrict__ selp,
        const unsigned short* __restrict__ NHb, float* __restrict__ out)
{
    int b = blockIdx.x >> 8, j = blockIdx.x & 255, t = threadIdx.x;
    int orig = selo[b * 256 + j];
    int p = selp[b * 256 + j];
    if (t == 0) out[b * 4096 + orig] = selv[b * 256 + j];
    const ushort4* src = (const ushort4*)(NHb + ((long)b * CMAX + p) * 256);
    ushort4 s = src[t];
    float4 o = make_float4(bf2f(s.x), bf2f(s.y), bf2f(s.z), bf2f(s.w));
    *(float4*)(out + 131072 + ((long)(b * 4096 + orig)) * 256 + t * 4) = o;
}

extern "C" void kernel_launch(void* const* d_in, const int* in_sizes, int n_in,
                              void* d_out, int out_size, void* d_ws, size_t ws_size,
                              hipStream_t stream)
{
    const float* act   = (const float*)d_in[0];
    const float* hid   = (const float*)d_in[1];
    const float* wi    = (const float*)d_in[2];
    const float* bi    = (const float*)d_in[3];
    const float* wo    = (const float*)d_in[4];
    const float* bo    = (const float*)d_in[5];
    const float* su_w1 = (const float*)d_in[6];
    const float* su_b1 = (const float*)d_in[7];
    const float* su_w2 = (const float*)d_in[8];
    const float* su_b2 = (const float*)d_in[9];
    const float* au_w1 = (const float*)d_in[10];
    const float* au_b1 = (const float*)d_in[11];
    const float* au_w2 = (const float*)d_in[12];
    const float* au_b2 = (const float*)d_in[13];
    const float* ln_g  = (const float*)d_in[14];
    const float* ln_b  = (const float*)d_in[15];
    float* out = (float*)d_out;

    char* ws = (char*)d_ws;
    size_t off = 0;
    auto alloc = [&](size_t bytes) {
        size_t o = off; off += (bytes + 255) & ~(size_t)255; return o;
    };
    float* svals = (float*)(ws + alloc((size_t)32 * 4096 * 4));
    int*   sidx  = (int*)  (ws + alloc((size_t)32 * 4096 * 4));
    int*   cnt   = (int*)  (ws + alloc(256));
    float* qkv   = (float*)(ws + alloc((size_t)32 * 256 * 768 * 4));
    float* Sb    = (float*)(ws + alloc((size_t)32 * 4 * 256 * 256 * 4));
    float* Ob    = (float*)(ws + alloc((size_t)32 * 256 * 256 * 4));
    float* MSG   = (float*)(ws + alloc((size_t)32 * 256 * 256 * 4));
    float* MSGC  = (float*)(ws + alloc((size_t)32 * 256 * 256 * 4));
    float* selv  = (float*)(ws + alloc((size_t)32 * 256 * 4));
    int*   selo  = (int*)  (ws + alloc((size_t)32 * 256 * 4));
    int*   selp  = (int*)  (ws + alloc((size_t)32 * 256 * 4));
    unsigned short* swb1 = (unsigned short*)(ws + alloc((size_t)256 * 512 * 2));
    unsigned short* swb2 = (unsigned short*)(ws + alloc((size_t)256 * 256 * 2));
    unsigned short* awb1 = (unsigned short*)(ws + alloc((size_t)256 * 512 * 2));
    unsigned short* Xb   = (unsigned short*)(ws + alloc((size_t)32 * CMAX * 256 * 2));
    unsigned short* H1b  = (unsigned short*)(ws + alloc((size_t)32 * CMAX * 256 * 2));
    unsigned short* NHb  = (unsigned short*)(ws + alloc((size_t)32 * CMAX * 256 * 2));
    float* nac = (float*)(ws + alloc((size_t)32 * CMAX * 4));
    float* Tb  = (float*)(ws + alloc(128));

    // 1. zero outputs
    fill0_k<<<2048, 256, 0, stream>>>((float4*)out, (long)out_size / 4);
    // 2. sort activations (topk_idx/vals + candidate count)
    topk1_k<<<32, 256, 0, stream>>>(act, svals, sidx, cnt);
    // 3. weight conversion (independent)
    convw_k<<<512, 256, 0, stream>>>(su_w1, su_w2, au_w1, swb1, swb2, awb1);
    // 4. gather + bf16 candidate rows
    gatherX_k<<<dim3(CMAX / 4, 32), 256, 0, stream>>>(hid, sidx, cnt, Xb);
    // 5. qkv = gather(hidden) @ wi^T + bi   [32 x 256 x 768]
    gemm_k<64, 256, 8, 8, true, true, 1><<<dim3(3, 4, 32), 256, 0, stream>>>(
        hid, 256, (long)4096 * 256, 0, 1,
        wi, 256, 0, 0, 1,
        qkv, 768, (long)256 * 768, 0, 1,
        256, bi, nullptr, 0, sidx, 4096, 0.f);
    // 6. S = q @ k^T / 8   per (b,h)
    gemm_k<64, 256, 8, 8, true, false, 3><<<dim3(1, 4, 128), 256, 0, stream>>>(
        qkv, 768, 196608, 64, 4,
        qkv + 256, 768, 196608, 64, 4,
        Sb, 256, 65536, 0, 1,
        64, nullptr, nullptr, 0, nullptr, 0, 0.125f);
    // 7. softmax rows
    softmax_k<<<8192, 256, 0, stream>>>(Sb);
    // 8. O = P @ V
    gemm_k<64, 64, 4, 4, false, false, 0><<<dim3(1, 4, 128), 256, 0, stream>>>(
        Sb, 256, 65536, 0, 1,
        qkv + 512, 768, 196608, 64, 4,
        Ob, 256, 65536, 64, 4,
        256, nullptr, nullptr, 0, nullptr, 0, 0.f);
    // 9. MSG = (O @ wo^T + bo) * topk_vals
    gemm_k<64, 256, 8, 8, true, false, 2><<<dim3(1, 4, 32), 256, 0, stream>>>(
        Ob, 256, 65536, 0, 1,
        wo, 256, 0, 0, 1,
        MSG, 256, 65536, 0, 1,
        256, bo, svals, 4096, nullptr, 0, 0.f);
    // 10. MSGC = MSG @ W1b^T   (message half of su_w1)
    gemm_k<64, 256, 8, 8, true, false, 0><<<dim3(1, 4, 32), 256, 0, stream>>>(
        MSG, 256, 65536, 0, 1,
        su_w1 + 256, 512, 0, 0, 1,
        MSGC, 256, 65536, 0, 1,
        256, nullptr, nullptr, 0, nullptr, 0, 0.f);
    // 11-13. candidate-row MLPs in bf16 MFMA
    dim3 mgrid(CMAX / 64, 32);
    mlp_mfma_k<1><<<mgrid, 256, 0, stream>>>(Xb, nullptr, swb1, 512, su_b1, MSGC,
        nullptr, nullptr, nullptr, nullptr, nullptr, cnt, H1b, nullptr);
    mlp_mfma_k<2><<<mgrid, 256, 0, stream>>>(H1b, nullptr, swb2, 256, su_b2, nullptr,
        ln_g, ln_b, nullptr, nullptr, nullptr, cnt, NHb, nullptr);
    mlp_mfma_k<3><<<mgrid, 256, 0, stream>>>(Xb, NHb, awb1, 512, au_b1, nullptr,
        nullptr, nullptr, au_w2, au_b2, svals, cnt, nullptr, nac);
    // 14. rank-256 value per batch
    selectT_k<<<32, 256, 0, stream>>>(nac, cnt, Tb);
    // 15. fp32 recompute of boundary-band rows
    bandfix_k<<<dim3(CMAX / 256, 32), 256, 0, stream>>>(hid, sidx, cnt, MSGC,
        su_w1, su_b1, su_w2, su_b2, ln_g, ln_b, au_w1, au_b1, au_w2, au_b2,
        svals, Tb, nac, NHb);
    // 16. top-k over corrected new activations
    topk2_k<<<32, 256, 0, stream>>>(nac, sidx, cnt, selv, selo, selp);
    // 17. scatter selected rows to output
    scatter_k<<<8192, 64, 0, stream>>>(selv, selo, selp, NHb, out);
}

// Round 3
// 1409.942 us; speedup vs baseline: 2.4636x; 2.4636x over previous
//
#include <hip/hip_runtime.h>

// NeuronInteraction: B=32, N=4096, D=256, H=4, hd=64, MSG_K=256, k=256
// Pipeline:
//  fill0 -> topk1(sort acts) -> convW(bf16 weights) -> gatherX(bf16 candidate rows)
//  -> fp32 attention chain (qkv, scores, softmax, PV, MSG, MSGC)
//  -> bf16 MFMA MLPs: su1 (gelu) -> su2 (+LN) -> au (gelu.dot+sigmoid)
//  -> selectT (rank-256 value) -> bandlist (compact band rows) ->
//  -> bandfix (fp32 recompute, ONE ROW PER BLOCK, parallel)
//  -> topk2 (sort candidates) -> scatter.
// Candidate pruning: rows with a < a*(256th) - 3/7 provably can't be selected.

constexpr int KC = 32;
constexpr int CMAX = 2304;           // E[cands]=2012, sigma~32 -> +9 sigma
constexpr float BAND_EPS = 0.01f;    // ~100x bf16-path na error bound
constexpr int MAXBAND = 512;         // E[band]~117, Poisson std ~11 -> huge margin

typedef short bf16x8 __attribute__((ext_vector_type(8)));
typedef float f32x4 __attribute__((ext_vector_type(4)));

__device__ __forceinline__ float gelu_f(float x) {
    return 0.5f * x * (1.0f + erff(x * 0.70710678118654752440f));
}
__device__ __forceinline__ unsigned short f2bf(float f) {
    unsigned u = __float_as_uint(f);
    return (unsigned short)((u + 0x7fffu + ((u >> 16) & 1u)) >> 16);
}
__device__ __forceinline__ float bf2f(unsigned short h) {
    return __uint_as_float(((unsigned)h) << 16);
}

// ---------------- zero-fill output ----------------
__global__ void __launch_bounds__(256) fill0_k(float4* p, long n4) {
    long i = (long)blockIdx.x * 256 + threadIdx.x;
    long stride = (long)gridDim.x * 256;
    float4 z = make_float4(0.f, 0.f, 0.f, 0.f);
    for (; i < n4; i += stride) p[i] = z;
}

// ---------------- top-k #1: full descending sort of activations ----------------
__global__ void __launch_bounds__(256) topk1_k(const float* __restrict__ act,
        float* __restrict__ svals, int* __restrict__ sidx, int* __restrict__ cnt)
{
    __shared__ unsigned long long keys[4096];
    int b = blockIdx.x, tid = threadIdx.x;
    for (int s = 0; s < 16; ++s) {
        int i = s * 256 + tid;
        unsigned vb = __float_as_uint(act[b * 4096 + i]);
        keys[i] = ((unsigned long long)vb << 32) | (unsigned)(~i);
    }
    __syncthreads();
    for (int k = 2; k <= 4096; k <<= 1) {
        for (int j = k >> 1; j > 0; j >>= 1) {
            for (int s = 0; s < 16; ++s) {
                int i = s * 256 + tid;
                int l = i ^ j;
                if (l > i) {
                    unsigned long long a = keys[i], c = keys[l];
                    bool sw = ((i & k) == 0) ? (a < c) : (a > c); // descending
                    if (sw) { keys[i] = c; keys[l] = a; }
                }
            }
            __syncthreads();
        }
    }
    float th = __uint_as_float((unsigned)(keys[255] >> 32)) - 0.4288f; // > 3/7 margin
    for (int s = 0; s < 16; ++s) {
        int i = s * 256 + tid;
        unsigned long long key = keys[i];
        float v = __uint_as_float((unsigned)(key >> 32));
        svals[b * 4096 + i] = v;
        sidx[b * 4096 + i] = (int)(~(unsigned)key);
        if (v >= th) {
            bool nxt = (i == 4095) ? false
                     : (__uint_as_float((unsigned)(keys[i + 1] >> 32)) >= th);
            if (!nxt) cnt[b] = (i + 1 < CMAX) ? (i + 1) : CMAX;
        }
    }
}

// ---------------- top-k #2: sort candidates by new activation ----------------
__global__ void __launch_bounds__(256) topk2_k(const float* __restrict__ newact,
        const int* __restrict__ sidx, const int* __restrict__ cnt,
        float* __restrict__ selv, int* __restrict__ selo, int* __restrict__ selp)
{
    __shared__ unsigned long long keys[4096];
    __shared__ unsigned short pay[4096];
    int b = blockIdx.x, tid = threadIdx.x;
    int C = min(cnt[b], CMAX);
    for (int s = 0; s < 16; ++s) {
        int i = s * 256 + tid;
        unsigned long long key = 0ull;
        if (i < C) {
            unsigned vb = __float_as_uint(newact[(long)b * CMAX + i]);
            unsigned orig = (unsigned)sidx[b * 4096 + i];
            key = ((unsigned long long)vb << 32) | (unsigned)(~orig);
        }
        keys[i] = key; pay[i] = (unsigned short)i;
    }
    __syncthreads();
    for (int k = 2; k <= 4096; k <<= 1) {
        for (int j = k >> 1; j > 0; j >>= 1) {
            for (int s = 0; s < 16; ++s) {
                int i = s * 256 + tid;
                int l = i ^ j;
                if (l > i) {
                    unsigned long long a = keys[i], c = keys[l];
                    bool sw = ((i & k) == 0) ? (a < c) : (a > c);
                    if (sw) {
                        keys[i] = c; keys[l] = a;
                        unsigned short t = pay[i]; pay[i] = pay[l]; pay[l] = t;
                    }
                }
            }
            __syncthreads();
        }
    }
    unsigned long long key = keys[tid];
    selv[b * 256 + tid] = __uint_as_float((unsigned)(key >> 32));
    selo[b * 256 + tid] = (int)(~(unsigned)key);
    selp[b * 256 + tid] = (int)pay[tid];
}

// ---------------- generic fp32 tiled GEMM (attention chain) ----------------
// EPI: 0 none, 1 +bias[n], 2 (+bias[n])*rowscale[m], 3 *cscale
template<int TM, int TN, int RM, int RN, bool BT, bool GATHER, int EPI>
__global__ void __launch_bounds__(256) gemm_k(
    const float* __restrict__ A, int lda, long sA1, long sA2, int divA,
    const float* __restrict__ B, int ldb, long sB1, long sB2, int divB,
    float* __restrict__ C, int ldc, long sC1, long sC2, int divC,
    int K, const float* __restrict__ bias, const float* __restrict__ rowscale,
    long rsStride, const int* __restrict__ gmap, long gmapStride, float cscale)
{
    constexpr int TX = TN / RN, TY = TM / RM;
    static_assert(TX * TY == 256, "block must be 256 threads");
    __shared__ float As[KC][TM + 4];
    __shared__ float Bs[KC][TN + 4];
    int z = blockIdx.z;
    const float* Ab = A + (long)(z / divA) * sA1 + (long)(z % divA) * sA2;
    const float* Bb = B + (long)(z / divB) * sB1 + (long)(z % divB) * sB2;
    float* Cb = C + (long)(z / divC) * sC1 + (long)(z % divC) * sC2;
    int m0 = blockIdx.y * TM, n0 = blockIdx.x * TN;
    int tid = threadIdx.x;
    int tx = tid % TX, ty = tid / TX;
    float acc[RM][RN];
    #pragma unroll
    for (int i = 0; i < RM; ++i)
        #pragma unroll
        for (int j = 0; j < RN; ++j) acc[i][j] = 0.f;

    for (int k0 = 0; k0 < K; k0 += KC) {
        __syncthreads();
        #pragma unroll
        for (int u = 0; u < (TM * KC) / 1024; ++u) {
            int idx = tid + u * 256;
            int m = idx / (KC / 4), k4 = idx % (KC / 4);
            int row = m0 + m;
            long grow = GATHER ? (long)gmap[(long)z * gmapStride + row] : (long)row;
            float4 v = *(const float4*)(Ab + grow * lda + k0 + k4 * 4);
            As[k4 * 4 + 0][m] = v.x; As[k4 * 4 + 1][m] = v.y;
            As[k4 * 4 + 2][m] = v.z; As[k4 * 4 + 3][m] = v.w;
        }
        if (BT) {
            #pragma unroll
            for (int u = 0; u < (TN * KC) / 1024; ++u) {
                int idx = tid + u * 256;
                int n = idx / (KC / 4), k4 = idx % (KC / 4);
                float4 v = *(const float4*)(Bb + (long)(n0 + n) * ldb + k0 + k4 * 4);
                Bs[k4 * 4 + 0][n] = v.x; Bs[k4 * 4 + 1][n] = v.y;
                Bs[k4 * 4 + 2][n] = v.z; Bs[k4 * 4 + 3][n] = v.w;
            }
        } else {
            #pragma unroll
            for (int u = 0; u < (TN * KC) / 1024; ++u) {
                int idx = tid + u * 256;
                int k = idx / (TN / 4), n4 = idx % (TN / 4);
                float4 v = *(const float4*)(Bb + (long)(k0 + k) * ldb + n0 + n4 * 4);
                *(float4*)&Bs[k][n4 * 4] = v;
            }
        }
        __syncthreads();
        #pragma unroll
        for (int k = 0; k < KC; ++k) {
            float av[RM], bv[RN];
            #pragma unroll
            for (int i = 0; i < RM; i += 4) {
                float4 t = *(const float4*)&As[k][ty * RM + i];
                av[i] = t.x; av[i + 1] = t.y; av[i + 2] = t.z; av[i + 3] = t.w;
            }
            #pragma unroll
            for (int j = 0; j < RN; j += 4) {
                float4 t = *(const float4*)&Bs[k][tx * RN + j];
                bv[j] = t.x; bv[j + 1] = t.y; bv[j + 2] = t.z; bv[j + 3] = t.w;
            }
            #pragma unroll
            for (int i = 0; i < RM; ++i)
                #pragma unroll
                for (int j = 0; j < RN; ++j)
                    acc[i][j] = fmaf(av[i], bv[j], acc[i][j]);
        }
    }
    #pragma unroll
    for (int i = 0; i < RM; ++i) {
        int gm = m0 + ty * RM + i;
        float rs = 1.f;
        if (EPI == 2) rs = rowscale[(long)z * rsStride + gm];
        #pragma unroll
        for (int j = 0; j < RN; j += 4) {
            int gn = n0 + tx * RN + j;
            float4 v = make_float4(acc[i][j], acc[i][j + 1], acc[i][j + 2], acc[i][j + 3]);
            if (EPI == 1 || EPI == 2) {
                float4 bb = *(const float4*)(bias + gn);
                v.x += bb.x; v.y += bb.y; v.z += bb.z; v.w += bb.w;
            }
            if (EPI == 2) { v.x *= rs; v.y *= rs; v.z *= rs; v.w *= rs; }
            if (EPI == 3) { v.x *= cscale; v.y *= cscale; v.z *= cscale; v.w *= cscale; }
            *(float4*)(Cb + (long)gm * ldc + gn) = v;
        }
    }
}

// ---------------- softmax over rows of 256 (1 wave / row) ----------------
__global__ void __launch_bounds__(256) softmax_k(float* __restrict__ S) {
    int row = blockIdx.x * 4 + (threadIdx.x >> 6);
    int lane = threadIdx.x & 63;
    float4* r = (float4*)(S + (long)row * 256);
    float4 v = r[lane];
    float m = fmaxf(fmaxf(v.x, v.y), fmaxf(v.z, v.w));
    for (int off = 32; off >= 1; off >>= 1) m = fmaxf(m, __shfl_xor(m, off));
    v.x = expf(v.x - m); v.y = expf(v.y - m); v.z = expf(v.z - m); v.w = expf(v.w - m);
    float s = v.x + v.y + v.z + v.w;
    for (int off = 32; off >= 1; off >>= 1) s += __shfl_xor(s, off);
    float inv = 1.f / s;
    v.x *= inv; v.y *= inv; v.z *= inv; v.w *= inv;
    r[lane] = v;
}

// ---------------- weight fp32->bf16 conversion ----------------
__global__ void __launch_bounds__(256) convw_k(
        const float* __restrict__ s1, const float* __restrict__ s2,
        const float* __restrict__ a1,
        unsigned short* __restrict__ o1, unsigned short* __restrict__ o2,
        unsigned short* __restrict__ o3)
{
    int i = blockIdx.x * 256 + threadIdx.x;   // grid 512 -> 131072
    o1[i] = f2bf(s1[i]);
    o3[i] = f2bf(a1[i]);
    if (i < 65536) o2[i] = f2bf(s2[i]);
}

// ---------------- gather candidate rows -> bf16 [B][CMAX][256] ----------------
__global__ void __launch_bounds__(256) gatherX_k(const float* __restrict__ hid,
        const int* __restrict__ sidx, const int* __restrict__ cnt,
        unsigned short* __restrict__ Xb)
{
    int b = blockIdx.y;
    int C = min(cnt[b], CMAX);
    int p = blockIdx.x * 4 + (threadIdx.x >> 6);
    int lane = threadIdx.x & 63;
    unsigned short* dst = Xb + ((long)b * CMAX + p) * 256 + lane * 4;
    if (p < C) {
        int row = sidx[b * 4096 + p];
        float4 v = *(const float4*)(hid + ((long)b * 4096 + row) * 256 + lane * 4);
        ushort4 o; o.x = f2bf(v.x); o.y = f2bf(v.y); o.z = f2bf(v.z); o.w = f2bf(v.w);
        *(ushort4*)dst = o;
    } else {
        ushort4 z; z.x = 0; z.y = 0; z.z = 0; z.w = 0;
        *(ushort4*)dst = z;
    }
}

// ---------------- bf16 MFMA MLP: block = 64 rows x 256 cols, 4 waves 1x4 ----
// STAGE 1: H1b = bf16(gelu(Xb@W1a^T + b1 + msgc))
// STAGE 2: NHb = bf16(LN(H1b@W2^T + b2))
// STAGE 3: nac = clip(0.7a + 0.3 sigmoid(gelu([Xb,NHb]@auW1^T + b1).w2 + b2))
template<int STAGE>
__global__ void __launch_bounds__(256, 2) mlp_mfma_k(
    const unsigned short* __restrict__ A0,
    const unsigned short* __restrict__ A1,
    const unsigned short* __restrict__ W, int ldw,
    const float* __restrict__ bias,
    const float* __restrict__ msgc,
    const float* __restrict__ lng, const float* __restrict__ lnb,
    const float* __restrict__ w2v, const float* __restrict__ b2s,
    const float* __restrict__ svals,
    const int* __restrict__ cnt,
    unsigned short* __restrict__ outb,
    float* __restrict__ nac)
{
    int b = blockIdx.y;
    int C = min(cnt[b], CMAX);
    int m0 = blockIdx.x * 64;
    if (m0 >= C) return;
    int tid = threadIdx.x;
    int wid = tid >> 6;
    int lane = tid & 63;
    int l15 = lane & 15;
    int q = lane >> 4;
    int n0w = wid * 64;

    f32x4 acc[4][4];
    #pragma unroll
    for (int mt = 0; mt < 4; ++mt)
        #pragma unroll
        for (int nt = 0; nt < 4; ++nt) {
            f32x4 z = {0.f, 0.f, 0.f, 0.f};
            acc[mt][nt] = z;
        }

    const unsigned short* Ab = A0 + ((long)b * CMAX + m0) * 256;
    const unsigned short* A1b = (STAGE == 3) ? (A1 + ((long)b * CMAX + m0) * 256) : nullptr;
    int aoff[4];
    #pragma unroll
    for (int mt = 0; mt < 4; ++mt) aoff[mt] = (mt * 16 + l15) * 256;
    const unsigned short* wr[4];
    #pragma unroll
    for (int nt = 0; nt < 4; ++nt) wr[nt] = W + (long)(n0w + nt * 16 + l15) * ldw;

    constexpr int KSTEPS = (STAGE == 3) ? 16 : 8;
    #pragma unroll 4
    for (int ks = 0; ks < KSTEPS; ++ks) {
        const unsigned short* As = (STAGE == 3 && ks >= 8) ? A1b : Ab;
        int ko = (STAGE == 3 && ks >= 8) ? (ks - 8) * 32 : ks * 32;
        int kw = ks * 32;
        bf16x8 af[4], bfr[4];
        #pragma unroll
        for (int mt = 0; mt < 4; ++mt)
            af[mt] = *(const bf16x8*)(As + aoff[mt] + ko + q * 8);
        #pragma unroll
        for (int nt = 0; nt < 4; ++nt)
            bfr[nt] = *(const bf16x8*)(wr[nt] + kw + q * 8);
        #pragma unroll
        for (int mt = 0; mt < 4; ++mt)
            #pragma unroll
            for (int nt = 0; nt < 4; ++nt)
                acc[mt][nt] = __builtin_amdgcn_mfma_f32_16x16x32_bf16(
                    af[mt], bfr[nt], acc[mt][nt], 0, 0, 0);
    }

    if constexpr (STAGE == 1) {
        float bb[4];
        #pragma unroll
        for (int nt = 0; nt < 4; ++nt) bb[nt] = bias[n0w + nt * 16 + l15];
        #pragma unroll
        for (int mt = 0; mt < 4; ++mt) {
            #pragma unroll
            for (int reg = 0; reg < 4; ++reg) {
                int p = m0 + mt * 16 + q * 4 + reg;
                long orow = ((long)b * CMAX + p) * 256;
                const float* mrow = msgc + ((long)b * 256 + p) * 256;
                bool hasm = (p < 256);
                #pragma unroll
                for (int nt = 0; nt < 4; ++nt) {
                    int gc = n0w + nt * 16 + l15;
                    float v = acc[mt][nt][reg] + bb[nt];
                    if (hasm) v += mrow[gc];
                    outb[orow + gc] = f2bf(gelu_f(v));
                }
            }
        }
    }

    if constexpr (STAGE == 2) {
        __shared__ float rsum[4][64];
        __shared__ float rsq[4][64];
        __shared__ float rmu[64], rrs[64];
        float bb[4], gg[4], eb[4];
        #pragma unroll
        for (int nt = 0; nt < 4; ++nt) {
            int gc = n0w + nt * 16 + l15;
            bb[nt] = bias[gc]; gg[nt] = lng[gc]; eb[nt] = lnb[gc];
        }
        #pragma unroll
        for (int mt = 0; mt < 4; ++mt)
            #pragma unroll
            for (int nt = 0; nt < 4; ++nt)
                #pragma unroll
                for (int reg = 0; reg < 4; ++reg)
                    acc[mt][nt][reg] += bb[nt];
        #pragma unroll
        for (int mt = 0; mt < 4; ++mt) {
            #pragma unroll
            for (int reg = 0; reg < 4; ++reg) {
                float s = 0.f, s2 = 0.f;
                #pragma unroll
                for (int nt = 0; nt < 4; ++nt) {
                    float v = acc[mt][nt][reg];
                    s += v; s2 += v * v;
                }
                #pragma unroll
                for (int off = 1; off <= 8; off <<= 1) {
                    s += __shfl_xor(s, off);
                    s2 += __shfl_xor(s2, off);
                }
                if (l15 == 0) {
                    int row = mt * 16 + q * 4 + reg;
                    rsum[wid][row] = s; rsq[wid][row] = s2;
                }
            }
        }
        __syncthreads();
        if (tid < 64) {
            float s = rsum[0][tid] + rsum[1][tid] + rsum[2][tid] + rsum[3][tid];
            float s2 = rsq[0][tid] + rsq[1][tid] + rsq[2][tid] + rsq[3][tid];
            float mu = s * (1.f / 256.f);
            float var = s2 * (1.f / 256.f) - mu * mu;
            rmu[tid] = mu;
            rrs[tid] = rsqrtf(var + 1e-5f);
        }
        __syncthreads();
        #pragma unroll
        for (int mt = 0; mt < 4; ++mt) {
            #pragma unroll
            for (int reg = 0; reg < 4; ++reg) {
                int row = mt * 16 + q * 4 + reg;
                int p = m0 + row;
                float mu = rmu[row], rs = rrs[row];
                long orow = ((long)b * CMAX + p) * 256;
                #pragma unroll
                for (int nt = 0; nt < 4; ++nt) {
                    int gc = n0w + nt * 16 + l15;
                    outb[orow + gc] = f2bf((acc[mt][nt][reg] - mu) * rs * gg[nt] + eb[nt]);
                }
            }
        }
    }

    if constexpr (STAGE == 3) {
        __shared__ float rsum[4][64];
        float bb[4], ww[4];
        #pragma unroll
        for (int nt = 0; nt < 4; ++nt) {
            int gc = n0w + nt * 16 + l15;
            bb[nt] = bias[gc]; ww[nt] = w2v[gc];
        }
        #pragma unroll
        for (int mt = 0; mt < 4; ++mt) {
            #pragma unroll
            for (int reg = 0; reg < 4; ++reg) {
                float s = 0.f;
                #pragma unroll
                for (int nt = 0; nt < 4; ++nt)
                    s += gelu_f(acc[mt][nt][reg] + bb[nt]) * ww[nt];
                #pragma unroll
                for (int off = 1; off <= 8; off <<= 1) s += __shfl_xor(s, off);
                if (l15 == 0) rsum[wid][mt * 16 + q * 4 + reg] = s;
            }
        }
        __syncthreads();
        if (tid < 64) {
            int p = m0 + tid;
            if (p < C) {
                float z = rsum[0][tid] + rsum[1][tid] + rsum[2][tid] + rsum[3][tid] + b2s[0];
                float delta = 1.f / (1.f + expf(-z));
                float na = 0.7f * svals[b * 4096 + p] + 0.3f * delta;
                nac[(long)b * CMAX + p] = fminf(fmaxf(na, 0.f), 1.f);
            }
        }
    }
}

// ---------------- rank-256 value via binary search ----------------
__global__ void __launch_bounds__(256) selectT_k(const float* __restrict__ nac,
        const int* __restrict__ cnt, float* __restrict__ T)
{
    __shared__ float v[CMAX];
    __shared__ int cs[256];
    __shared__ float bounds[2];
    int b = blockIdx.x, tid = threadIdx.x;
    int C = min(cnt[b], CMAX);
    for (int i = tid; i < CMAX; i += 256)
        v[i] = (i < C) ? nac[(long)b * CMAX + i] : -1.f;
    if (tid == 0) { bounds[0] = 0.f; bounds[1] = 1.0f; }
    __syncthreads();
    for (int it = 0; it < 30; ++it) {
        float mid = 0.5f * (bounds[0] + bounds[1]);
        int c = 0;
        for (int i = tid; i < CMAX; i += 256) c += (v[i] >= mid) ? 1 : 0;
        cs[tid] = c; __syncthreads();
        for (int s = 128; s; s >>= 1) {
            if (tid < s) cs[tid] += cs[tid + s];
            __syncthreads();
        }
        if (tid == 0) { if (cs[0] >= 256) bounds[0] = mid; else bounds[1] = mid; }
        __syncthreads();
    }
    if (tid == 0) T[b] = bounds[0];
}

// ---------------- compact band rows into a per-batch list ----------------
__global__ void __launch_bounds__(256) bandlist_k(const float* __restrict__ nac,
        const int* __restrict__ cnt, const float* __restrict__ Tarr,
        int* __restrict__ bandlist, int* __restrict__ bandcnt)
{
    int b = blockIdx.y;
    int C = min(cnt[b], CMAX);
    int p = blockIdx.x * 256 + threadIdx.x;
    if (p < C && fabsf(nac[(long)b * CMAX + p] - Tarr[b]) < BAND_EPS) {
        int slot = atomicAdd(&bandcnt[b], 1);
        if (slot < MAXBAND) bandlist[b * MAXBAND + slot] = p;
    }
}

__device__ __forceinline__ float blk_reduce(float x, float* red, int tid) {
    red[tid] = x; __syncthreads();
    for (int s = 128; s; s >>= 1) {
        if (tid < s) red[tid] += red[tid + s];
        __syncthreads();
    }
    float r = red[0]; __syncthreads();
    return r;
}

// ---------------- fp32 recompute: ONE band row per block (parallel) --------
__global__ void __launch_bounds__(256) bandfix_k(
    const float* __restrict__ hid, const int* __restrict__ sidx,
    const int* __restrict__ cnt, const float* __restrict__ msgc,
    const float* __restrict__ su_w1, const float* __restrict__ su_b1,
    const float* __restrict__ su_w2, const float* __restrict__ su_b2,
    const float* __restrict__ ln_g, const float* __restrict__ ln_b,
    const float* __restrict__ au_w1, const float* __restrict__ au_b1,
    const float* __restrict__ au_w2, const float* __restrict__ au_b2,
    const float* __restrict__ svals,
    const int* __restrict__ bandlist, const int* __restrict__ bandcnt,
    float* __restrict__ nac, unsigned short* __restrict__ NHb)
{
    int b = blockIdx.y;
    int slot = blockIdx.x;
    int M = min(bandcnt[b], MAXBAND);
    if (slot >= M) return;
    int pp = bandlist[b * MAXBAND + slot];
    int tid = threadIdx.x;
    __shared__ float xr[256], h1[256], nh[256], red[256];
    int row = sidx[b * 4096 + pp];
    int n = tid;
    xr[n] = hid[((long)b * 4096 + row) * 256 + n];
    __syncthreads();
    // su stage 1
    float s = su_b1[n];
    if (pp < 256) s += msgc[((long)b * 256 + pp) * 256 + n];
    {
        const float* w = su_w1 + (long)n * 512;
        #pragma unroll 4
        for (int k = 0; k < 256; k += 4) {
            float4 wv = *(const float4*)(w + k);
            s += xr[k] * wv.x + xr[k + 1] * wv.y + xr[k + 2] * wv.z + xr[k + 3] * wv.w;
        }
    }
    h1[n] = gelu_f(s);
    __syncthreads();
    // su stage 2 + LN
    float y = su_b2[n];
    {
        const float* w = su_w2 + (long)n * 256;
        #pragma unroll 4
        for (int k = 0; k < 256; k += 4) {
            float4 wv = *(const float4*)(w + k);
            y += h1[k] * wv.x + h1[k + 1] * wv.y + h1[k + 2] * wv.z + h1[k + 3] * wv.w;
        }
    }
    float mu = blk_reduce(y, red, tid) * (1.f / 256.f);
    float d = y - mu;
    float var = blk_reduce(d * d, red, tid) * (1.f / 256.f);
    float o = d * rsqrtf(var + 1e-5f) * ln_g[n] + ln_b[n];
    nh[n] = o;
    NHb[((long)b * CMAX + pp) * 256 + n] = f2bf(o);
    __syncthreads();
    // au
    float ax = au_b1[n];
    {
        const float* w = au_w1 + (long)n * 512;
        #pragma unroll 4
        for (int k = 0; k < 256; k += 4) {
            float4 wv = *(const float4*)(w + k);
            ax += xr[k] * wv.x + xr[k + 1] * wv.y + xr[k + 2] * wv.z + xr[k + 3] * wv.w;
        }
        const float* w2 = w + 256;
        #pragma unroll 4
        for (int k = 0; k < 256; k += 4) {
            float4 wv = *(const float4*)(w2 + k);
            ax += nh[k] * wv.x + nh[k + 1] * wv.y + nh[k + 2] * wv.z + nh[k + 3] * wv.w;
        }
    }
    float z = blk_reduce(gelu_f(ax) * au_w2[n], red, tid) + au_b2[0];
    if (tid == 0) {
        float delta = 1.f / (1.f + expf(-z));
        float na = 0.7f * svals[b * 4096 + pp] + 0.3f * delta;
        nac[(long)b * CMAX + pp] = fminf(fmaxf(na, 0.f), 1.f);
    }
}

// ---------------- scatter outputs ----------------
__global__ void __launch_bounds__(64) scatter_k(const float* __restrict__ selv,
        const int* __restrict__ selo, const int* __restrict__ selp,
        const unsigned short* __restrict__ NHb, float* __restrict__ out)
{
    int b = blockIdx.x >> 8, j = blockIdx.x & 255, t = threadIdx.x;
    int orig = selo[b * 256 + j];
    int p = selp[b * 256 + j];
    if (t == 0) out[b * 4096 + orig] = selv[b * 256 + j];
    const ushort4* src = (const ushort4*)(NHb + ((long)b * CMAX + p) * 256);
    ushort4 s = src[t];
    float4 o = make_float4(bf2f(s.x), bf2f(s.y), bf2f(s.z), bf2f(s.w));
    *(float4*)(out + 131072 + ((long)(b * 4096 + orig)) * 256 + t * 4) = o;
}

extern "C" void kernel_launch(void* const* d_in, const int* in_sizes, int n_in,
                              void* d_out, int out_size, void* d_ws, size_t ws_size,
                              hipStream_t stream)
{
    const float* act   = (const float*)d_in[0];
    const float* hid   = (const float*)d_in[1];
    const float* wi    = (const float*)d_in[2];
    const float* bi    = (const float*)d_in[3];
    const float* wo    = (const float*)d_in[4];
    const float* bo    = (const float*)d_in[5];
    const float* su_w1 = (const float*)d_in[6];
    const float* su_b1 = (const float*)d_in[7];
    const float* su_w2 = (const float*)d_in[8];
    const float* su_b2 = (const float*)d_in[9];
    const float* au_w1 = (const float*)d_in[10];
    const float* au_b1 = (const float*)d_in[11];
    const float* au_w2 = (const float*)d_in[12];
    const float* au_b2 = (const float*)d_in[13];
    const float* ln_g  = (const float*)d_in[14];
    const float* ln_b  = (const float*)d_in[15];
    float* out = (float*)d_out;

    char* ws = (char*)d_ws;
    size_t off = 0;
    auto alloc = [&](size_t bytes) {
        size_t o = off; off += (bytes + 255) & ~(size_t)255; return o;
    };
    float* svals = (float*)(ws + alloc((size_t)32 * 4096 * 4));
    int*   sidx  = (int*)  (ws + alloc((size_t)32 * 4096 * 4));
    int*   cnt   = (int*)  (ws + alloc(256));
    float* qkv   = (float*)(ws + alloc((size_t)32 * 256 * 768 * 4));
    float* Sb    = (float*)(ws + alloc((size_t)32 * 4 * 256 * 256 * 4));
    float* Ob    = (float*)(ws + alloc((size_t)32 * 256 * 256 * 4));
    float* MSG   = (float*)(ws + alloc((size_t)32 * 256 * 256 * 4));
    float* MSGC  = (float*)(ws + alloc((size_t)32 * 256 * 256 * 4));
    float* selv  = (float*)(ws + alloc((size_t)32 * 256 * 4));
    int*   selo  = (int*)  (ws + alloc((size_t)32 * 256 * 4));
    int*   selp  = (int*)  (ws + alloc((size_t)32 * 256 * 4));
    unsigned short* swb1 = (unsigned short*)(ws + alloc((size_t)256 * 512 * 2));
    unsigned short* swb2 = (unsigned short*)(ws + alloc((size_t)256 * 256 * 2));
    unsigned short* awb1 = (unsigned short*)(ws + alloc((size_t)256 * 512 * 2));
    unsigned short* Xb   = (unsigned short*)(ws + alloc((size_t)32 * CMAX * 256 * 2));
    unsigned short* H1b  = (unsigned short*)(ws + alloc((size_t)32 * CMAX * 256 * 2));
    unsigned short* NHb  = (unsigned short*)(ws + alloc((size_t)32 * CMAX * 256 * 2));
    float* nac = (float*)(ws + alloc((size_t)32 * CMAX * 4));
    float* Tb  = (float*)(ws + alloc(128));
    int* bandlist = (int*)(ws + alloc((size_t)32 * MAXBAND * 4));
    int* bandcnt  = (int*)(ws + alloc(128));

    // 0. zero band counters (d_ws is re-poisoned 0xAA before every call)
    hipMemsetAsync(bandcnt, 0, 32 * sizeof(int), stream);
    // 1. zero outputs
    fill0_k<<<2048, 256, 0, stream>>>((float4*)out, (long)out_size / 4);
    // 2. sort activations (topk_idx/vals + candidate count)
    topk1_k<<<32, 256, 0, stream>>>(act, svals, sidx, cnt);
    // 3. weight conversion (independent)
    convw_k<<<512, 256, 0, stream>>>(su_w1, su_w2, au_w1, swb1, swb2, awb1);
    // 4. gather + bf16 candidate rows
    gatherX_k<<<dim3(CMAX / 4, 32), 256, 0, stream>>>(hid, sidx, cnt, Xb);
    // 5. qkv = gather(hidden) @ wi^T + bi   [32 x 256 x 768]
    gemm_k<64, 256, 8, 8, true, true, 1><<<dim3(3, 4, 32), 256, 0, stream>>>(
        hid, 256, (long)4096 * 256, 0, 1,
        wi, 256, 0, 0, 1,
        qkv, 768, (long)256 * 768, 0, 1,
        256, bi, nullptr, 0, sidx, 4096, 0.f);
    // 6. S = q @ k^T / 8   per (b,h)
    gemm_k<64, 256, 8, 8, true, false, 3><<<dim3(1, 4, 128), 256, 0, stream>>>(
        qkv, 768, 196608, 64, 4,
        qkv + 256, 768, 196608, 64, 4,
        Sb, 256, 65536, 0, 1,
        64, nullptr, nullptr, 0, nullptr, 0, 0.125f);
    // 7. softmax rows
    softmax_k<<<8192, 256, 0, stream>>>(Sb);
    // 8. O = P @ V
    gemm_k<64, 64, 4, 4, false, false, 0><<<dim3(1, 4, 128), 256, 0, stream>>>(
        Sb, 256, 65536, 0, 1,
        qkv + 512, 768, 196608, 64, 4,
        Ob, 256, 65536, 64, 4,
        256, nullptr, nullptr, 0, nullptr, 0, 0.f);
    // 9. MSG = (O @ wo^T + bo) * topk_vals
    gemm_k<64, 256, 8, 8, true, false, 2><<<dim3(1, 4, 32), 256, 0, stream>>>(
        Ob, 256, 65536, 0, 1,
        wo, 256, 0, 0, 1,
        MSG, 256, 65536, 0, 1,
        256, bo, svals, 4096, nullptr, 0, 0.f);
    // 10. MSGC = MSG @ W1b^T   (message half of su_w1)
    gemm_k<64, 256, 8, 8, true, false, 0><<<dim3(1, 4, 32), 256, 0, stream>>>(
        MSG, 256, 65536, 0, 1,
        su_w1 + 256, 512, 0, 0, 1,
        MSGC, 256, 65536, 0, 1,
        256, nullptr, nullptr, 0, nullptr, 0, 0.f);
    // 11-13. candidate-row MLPs in bf16 MFMA
    dim3 mgrid(CMAX / 64, 32);
    mlp_mfma_k<1><<<mgrid, 256, 0, stream>>>(Xb, nullptr, swb1, 512, su_b1, MSGC,
        nullptr, nullptr, nullptr, nullptr, nullptr, cnt, H1b, nullptr);
    mlp_mfma_k<2><<<mgrid, 256, 0, stream>>>(H1b, nullptr, swb2, 256, su_b2, nullptr,
        ln_g, ln_b, nullptr, nullptr, nullptr, cnt, NHb, nullptr);
    mlp_mfma_k<3><<<mgrid, 256, 0, stream>>>(Xb, NHb, awb1, 512, au_b1, nullptr,
        nullptr, nullptr, au_w2, au_b2, svals, cnt, nullptr, nac);
    // 14. rank-256 value per batch
    selectT_k<<<32, 256, 0, stream>>>(nac, cnt, Tb);
    // 15a. compact band rows
    bandlist_k<<<dim3(CMAX / 256, 32), 256, 0, stream>>>(nac, cnt, Tb, bandlist, bandcnt);
    // 15b. fp32 recompute of boundary-band rows, one row per block
    bandfix_k<<<dim3(MAXBAND, 32), 256, 0, stream>>>(hid, sidx, cnt, MSGC,
        su_w1, su_b1, su_w2, su_b2, ln_g, ln_b, au_w1, au_b1, au_w2, au_b2,
        svals, bandlist, bandcnt, nac, NHb);
    // 16. top-k over corrected new activations
    topk2_k<<<32, 256, 0, stream>>>(nac, sidx, cnt, selv, selo, selp);
    // 17. scatter selected rows to output
    scatter_k<<<8192, 64, 0, stream>>>(selv, selo, selp, NHb, out);
}

// Round 4
// 1033.858 us; speedup vs baseline: 3.3598x; 1.3638x over previous
//
#include <hip/hip_runtime.h>

// NeuronInteraction: B=32, N=4096, D=256, H=4, hd=64, MSG_K=256, k=256
// Pipeline:
//  fill0 -> topk1(sort acts) -> convW(bf16 weights) -> transT(fp32 W^T) ->
//  gatherX(bf16 candidate rows) -> fp32 attention chain -> bf16 MFMA MLPs ->
//  selectT -> bandlist -> bandfix (fp32 recompute, 8 rows/block, coalesced W^T)
//  -> topk2 -> scatter.
// Candidate pruning: rows with a < a*(256th) - 3/7 provably can't be selected.

constexpr int KC = 32;
constexpr int CMAX = 2304;           // E[cands]=2012, sigma~32 -> +9 sigma
constexpr float BAND_EPS = 0.01f;    // ~13x bf16-path na error bound
constexpr int MAXBAND = 512;         // E[band]~117 -> huge margin

typedef short bf16x8 __attribute__((ext_vector_type(8)));
typedef float f32x4 __attribute__((ext_vector_type(4)));

__device__ __forceinline__ float gelu_f(float x) {
    return 0.5f * x * (1.0f + erff(x * 0.70710678118654752440f));
}
__device__ __forceinline__ unsigned short f2bf(float f) {
    unsigned u = __float_as_uint(f);
    return (unsigned short)((u + 0x7fffu + ((u >> 16) & 1u)) >> 16);
}
__device__ __forceinline__ float bf2f(unsigned short h) {
    return __uint_as_float(((unsigned)h) << 16);
}

// ---------------- zero-fill output ----------------
__global__ void __launch_bounds__(256) fill0_k(float4* p, long n4) {
    long i = (long)blockIdx.x * 256 + threadIdx.x;
    long stride = (long)gridDim.x * 256;
    float4 z = make_float4(0.f, 0.f, 0.f, 0.f);
    for (; i < n4; i += stride) p[i] = z;
}

// ---------------- top-k #1: full descending sort of activations ----------------
__global__ void __launch_bounds__(256) topk1_k(const float* __restrict__ act,
        float* __restrict__ svals, int* __restrict__ sidx, int* __restrict__ cnt)
{
    __shared__ unsigned long long keys[4096];
    int b = blockIdx.x, tid = threadIdx.x;
    for (int s = 0; s < 16; ++s) {
        int i = s * 256 + tid;
        unsigned vb = __float_as_uint(act[b * 4096 + i]);
        keys[i] = ((unsigned long long)vb << 32) | (unsigned)(~i);
    }
    __syncthreads();
    for (int k = 2; k <= 4096; k <<= 1) {
        for (int j = k >> 1; j > 0; j >>= 1) {
            for (int s = 0; s < 16; ++s) {
                int i = s * 256 + tid;
                int l = i ^ j;
                if (l > i) {
                    unsigned long long a = keys[i], c = keys[l];
                    bool sw = ((i & k) == 0) ? (a < c) : (a > c); // descending
                    if (sw) { keys[i] = c; keys[l] = a; }
                }
            }
            __syncthreads();
        }
    }
    float th = __uint_as_float((unsigned)(keys[255] >> 32)) - 0.4288f; // > 3/7 margin
    for (int s = 0; s < 16; ++s) {
        int i = s * 256 + tid;
        unsigned long long key = keys[i];
        float v = __uint_as_float((unsigned)(key >> 32));
        svals[b * 4096 + i] = v;
        sidx[b * 4096 + i] = (int)(~(unsigned)key);
        if (v >= th) {
            bool nxt = (i == 4095) ? false
                     : (__uint_as_float((unsigned)(keys[i + 1] >> 32)) >= th);
            if (!nxt) cnt[b] = (i + 1 < CMAX) ? (i + 1) : CMAX;
        }
    }
}

// ---------------- top-k #2: sort candidates by new activation ----------------
__global__ void __launch_bounds__(256) topk2_k(const float* __restrict__ newact,
        const int* __restrict__ sidx, const int* __restrict__ cnt,
        float* __restrict__ selv, int* __restrict__ selo, int* __restrict__ selp)
{
    __shared__ unsigned long long keys[4096];
    __shared__ unsigned short pay[4096];
    int b = blockIdx.x, tid = threadIdx.x;
    int C = min(cnt[b], CMAX);
    for (int s = 0; s < 16; ++s) {
        int i = s * 256 + tid;
        unsigned long long key = 0ull;
        if (i < C) {
            unsigned vb = __float_as_uint(newact[(long)b * CMAX + i]);
            unsigned orig = (unsigned)sidx[b * 4096 + i];
            key = ((unsigned long long)vb << 32) | (unsigned)(~orig);
        }
        keys[i] = key; pay[i] = (unsigned short)i;
    }
    __syncthreads();
    for (int k = 2; k <= 4096; k <<= 1) {
        for (int j = k >> 1; j > 0; j >>= 1) {
            for (int s = 0; s < 16; ++s) {
                int i = s * 256 + tid;
                int l = i ^ j;
                if (l > i) {
                    unsigned long long a = keys[i], c = keys[l];
                    bool sw = ((i & k) == 0) ? (a < c) : (a > c);
                    if (sw) {
                        keys[i] = c; keys[l] = a;
                        unsigned short t = pay[i]; pay[i] = pay[l]; pay[l] = t;
                    }
                }
            }
            __syncthreads();
        }
    }
    unsigned long long key = keys[tid];
    selv[b * 256 + tid] = __uint_as_float((unsigned)(key >> 32));
    selo[b * 256 + tid] = (int)(~(unsigned)key);
    selp[b * 256 + tid] = (int)pay[tid];
}

// ---------------- generic fp32 tiled GEMM (attention chain) ----------------
// EPI: 0 none, 1 +bias[n], 2 (+bias[n])*rowscale[m], 3 *cscale
template<int TM, int TN, int RM, int RN, bool BT, bool GATHER, int EPI>
__global__ void __launch_bounds__(256) gemm_k(
    const float* __restrict__ A, int lda, long sA1, long sA2, int divA,
    const float* __restrict__ B, int ldb, long sB1, long sB2, int divB,
    float* __restrict__ C, int ldc, long sC1, long sC2, int divC,
    int K, const float* __restrict__ bias, const float* __restrict__ rowscale,
    long rsStride, const int* __restrict__ gmap, long gmapStride, float cscale)
{
    constexpr int TX = TN / RN, TY = TM / RM;
    static_assert(TX * TY == 256, "block must be 256 threads");
    __shared__ float As[KC][TM + 4];
    __shared__ float Bs[KC][TN + 4];
    int z = blockIdx.z;
    const float* Ab = A + (long)(z / divA) * sA1 + (long)(z % divA) * sA2;
    const float* Bb = B + (long)(z / divB) * sB1 + (long)(z % divB) * sB2;
    float* Cb = C + (long)(z / divC) * sC1 + (long)(z % divC) * sC2;
    int m0 = blockIdx.y * TM, n0 = blockIdx.x * TN;
    int tid = threadIdx.x;
    int tx = tid % TX, ty = tid / TX;
    float acc[RM][RN];
    #pragma unroll
    for (int i = 0; i < RM; ++i)
        #pragma unroll
        for (int j = 0; j < RN; ++j) acc[i][j] = 0.f;

    for (int k0 = 0; k0 < K; k0 += KC) {
        __syncthreads();
        #pragma unroll
        for (int u = 0; u < (TM * KC) / 1024; ++u) {
            int idx = tid + u * 256;
            int m = idx / (KC / 4), k4 = idx % (KC / 4);
            int row = m0 + m;
            long grow = GATHER ? (long)gmap[(long)z * gmapStride + row] : (long)row;
            float4 v = *(const float4*)(Ab + grow * lda + k0 + k4 * 4);
            As[k4 * 4 + 0][m] = v.x; As[k4 * 4 + 1][m] = v.y;
            As[k4 * 4 + 2][m] = v.z; As[k4 * 4 + 3][m] = v.w;
        }
        if (BT) {
            #pragma unroll
            for (int u = 0; u < (TN * KC) / 1024; ++u) {
                int idx = tid + u * 256;
                int n = idx / (KC / 4), k4 = idx % (KC / 4);
                float4 v = *(const float4*)(Bb + (long)(n0 + n) * ldb + k0 + k4 * 4);
                Bs[k4 * 4 + 0][n] = v.x; Bs[k4 * 4 + 1][n] = v.y;
                Bs[k4 * 4 + 2][n] = v.z; Bs[k4 * 4 + 3][n] = v.w;
            }
        } else {
            #pragma unroll
            for (int u = 0; u < (TN * KC) / 1024; ++u) {
                int idx = tid + u * 256;
                int k = idx / (TN / 4), n4 = idx % (TN / 4);
                float4 v = *(const float4*)(Bb + (long)(k0 + k) * ldb + n0 + n4 * 4);
                *(float4*)&Bs[k][n4 * 4] = v;
            }
        }
        __syncthreads();
        #pragma unroll
        for (int k = 0; k < KC; ++k) {
            float av[RM], bv[RN];
            #pragma unroll
            for (int i = 0; i < RM; i += 4) {
                float4 t = *(const float4*)&As[k][ty * RM + i];
                av[i] = t.x; av[i + 1] = t.y; av[i + 2] = t.z; av[i + 3] = t.w;
            }
            #pragma unroll
            for (int j = 0; j < RN; j += 4) {
                float4 t = *(const float4*)&Bs[k][tx * RN + j];
                bv[j] = t.x; bv[j + 1] = t.y; bv[j + 2] = t.z; bv[j + 3] = t.w;
            }
            #pragma unroll
            for (int i = 0; i < RM; ++i)
                #pragma unroll
                for (int j = 0; j < RN; ++j)
                    acc[i][j] = fmaf(av[i], bv[j], acc[i][j]);
        }
    }
    #pragma unroll
    for (int i = 0; i < RM; ++i) {
        int gm = m0 + ty * RM + i;
        float rs = 1.f;
        if (EPI == 2) rs = rowscale[(long)z * rsStride + gm];
        #pragma unroll
        for (int j = 0; j < RN; j += 4) {
            int gn = n0 + tx * RN + j;
            float4 v = make_float4(acc[i][j], acc[i][j + 1], acc[i][j + 2], acc[i][j + 3]);
            if (EPI == 1 || EPI == 2) {
                float4 bb = *(const float4*)(bias + gn);
                v.x += bb.x; v.y += bb.y; v.z += bb.z; v.w += bb.w;
            }
            if (EPI == 2) { v.x *= rs; v.y *= rs; v.z *= rs; v.w *= rs; }
            if (EPI == 3) { v.x *= cscale; v.y *= cscale; v.z *= cscale; v.w *= cscale; }
            *(float4*)(Cb + (long)gm * ldc + gn) = v;
        }
    }
}

// ---------------- softmax over rows of 256 (1 wave / row) ----------------
__global__ void __launch_bounds__(256) softmax_k(float* __restrict__ S) {
    int row = blockIdx.x * 4 + (threadIdx.x >> 6);
    int lane = threadIdx.x & 63;
    float4* r = (float4*)(S + (long)row * 256);
    float4 v = r[lane];
    float m = fmaxf(fmaxf(v.x, v.y), fmaxf(v.z, v.w));
    for (int off = 32; off >= 1; off >>= 1) m = fmaxf(m, __shfl_xor(m, off));
    v.x = expf(v.x - m); v.y = expf(v.y - m); v.z = expf(v.z - m); v.w = expf(v.w - m);
    float s = v.x + v.y + v.z + v.w;
    for (int off = 32; off >= 1; off >>= 1) s += __shfl_xor(s, off);
    float inv = 1.f / s;
    v.x *= inv; v.y *= inv; v.z *= inv; v.w *= inv;
    r[lane] = v;
}

// ---------------- weight fp32->bf16 conversion ----------------
__global__ void __launch_bounds__(256) convw_k(
        const float* __restrict__ s1, const float* __restrict__ s2,
        const float* __restrict__ a1,
        unsigned short* __restrict__ o1, unsigned short* __restrict__ o2,
        unsigned short* __restrict__ o3)
{
    int i = blockIdx.x * 256 + threadIdx.x;   // grid 512 -> 131072
    o1[i] = f2bf(s1[i]);
    o3[i] = f2bf(a1[i]);
    if (i < 65536) o2[i] = f2bf(s2[i]);
}

// ---------------- fp32 weight transpose: dst[k][n] = src[n][koff+k] ----------
// grid (K/32, 8), block 256 = (32 x, 8 y). dst is K x 256.
__global__ void __launch_bounds__(256) transT_k(const float* __restrict__ src,
        int ld, int koff, float* __restrict__ dst)
{
    __shared__ float t[32][33];
    int k0 = blockIdx.x * 32, n0 = blockIdx.y * 32;
    int tx = threadIdx.x & 31, ty = threadIdx.x >> 5;
    #pragma unroll
    for (int yy = 0; yy < 4; ++yy) {
        int nl = ty * 4 + yy;
        t[nl][tx] = src[(long)(n0 + nl) * ld + koff + k0 + tx];
    }
    __syncthreads();
    #pragma unroll
    for (int yy = 0; yy < 4; ++yy) {
        int kl = ty * 4 + yy;
        dst[(long)(k0 + kl) * 256 + n0 + tx] = t[tx][kl];
    }
}

// ---------------- gather candidate rows -> bf16 [B][CMAX][256] ----------------
__global__ void __launch_bounds__(256) gatherX_k(const float* __restrict__ hid,
        const int* __restrict__ sidx, const int* __restrict__ cnt,
        unsigned short* __restrict__ Xb)
{
    int b = blockIdx.y;
    int C = min(cnt[b], CMAX);
    int p = blockIdx.x * 4 + (threadIdx.x >> 6);
    int lane = threadIdx.x & 63;
    unsigned short* dst = Xb + ((long)b * CMAX + p) * 256 + lane * 4;
    if (p < C) {
        int row = sidx[b * 4096 + p];
        float4 v = *(const float4*)(hid + ((long)b * 4096 + row) * 256 + lane * 4);
        ushort4 o; o.x = f2bf(v.x); o.y = f2bf(v.y); o.z = f2bf(v.z); o.w = f2bf(v.w);
        *(ushort4*)dst = o;
    } else {
        ushort4 z; z.x = 0; z.y = 0; z.z = 0; z.w = 0;
        *(ushort4*)dst = z;
    }
}

// ---------------- bf16 MFMA MLP: block = 64 rows x 256 cols, 4 waves 1x4 ----
template<int STAGE>
__global__ void __launch_bounds__(256, 2) mlp_mfma_k(
    const unsigned short* __restrict__ A0,
    const unsigned short* __restrict__ A1,
    const unsigned short* __restrict__ W, int ldw,
    const float* __restrict__ bias,
    const float* __restrict__ msgc,
    const float* __restrict__ lng, const float* __restrict__ lnb,
    const float* __restrict__ w2v, const float* __restrict__ b2s,
    const float* __restrict__ svals,
    const int* __restrict__ cnt,
    unsigned short* __restrict__ outb,
    float* __restrict__ nac)
{
    int b = blockIdx.y;
    int C = min(cnt[b], CMAX);
    int m0 = blockIdx.x * 64;
    if (m0 >= C) return;
    int tid = threadIdx.x;
    int wid = tid >> 6;
    int lane = tid & 63;
    int l15 = lane & 15;
    int q = lane >> 4;
    int n0w = wid * 64;

    f32x4 acc[4][4];
    #pragma unroll
    for (int mt = 0; mt < 4; ++mt)
        #pragma unroll
        for (int nt = 0; nt < 4; ++nt) {
            f32x4 z = {0.f, 0.f, 0.f, 0.f};
            acc[mt][nt] = z;
        }

    const unsigned short* Ab = A0 + ((long)b * CMAX + m0) * 256;
    const unsigned short* A1b = (STAGE == 3) ? (A1 + ((long)b * CMAX + m0) * 256) : nullptr;
    int aoff[4];
    #pragma unroll
    for (int mt = 0; mt < 4; ++mt) aoff[mt] = (mt * 16 + l15) * 256;
    const unsigned short* wr[4];
    #pragma unroll
    for (int nt = 0; nt < 4; ++nt) wr[nt] = W + (long)(n0w + nt * 16 + l15) * ldw;

    constexpr int KSTEPS = (STAGE == 3) ? 16 : 8;
    #pragma unroll 4
    for (int ks = 0; ks < KSTEPS; ++ks) {
        const unsigned short* As = (STAGE == 3 && ks >= 8) ? A1b : Ab;
        int ko = (STAGE == 3 && ks >= 8) ? (ks - 8) * 32 : ks * 32;
        int kw = ks * 32;
        bf16x8 af[4], bfr[4];
        #pragma unroll
        for (int mt = 0; mt < 4; ++mt)
            af[mt] = *(const bf16x8*)(As + aoff[mt] + ko + q * 8);
        #pragma unroll
        for (int nt = 0; nt < 4; ++nt)
            bfr[nt] = *(const bf16x8*)(wr[nt] + kw + q * 8);
        #pragma unroll
        for (int mt = 0; mt < 4; ++mt)
            #pragma unroll
            for (int nt = 0; nt < 4; ++nt)
                acc[mt][nt] = __builtin_amdgcn_mfma_f32_16x16x32_bf16(
                    af[mt], bfr[nt], acc[mt][nt], 0, 0, 0);
    }

    if constexpr (STAGE == 1) {
        float bb[4];
        #pragma unroll
        for (int nt = 0; nt < 4; ++nt) bb[nt] = bias[n0w + nt * 16 + l15];
        #pragma unroll
        for (int mt = 0; mt < 4; ++mt) {
            #pragma unroll
            for (int reg = 0; reg < 4; ++reg) {
                int p = m0 + mt * 16 + q * 4 + reg;
                long orow = ((long)b * CMAX + p) * 256;
                const float* mrow = msgc + ((long)b * 256 + p) * 256;
                bool hasm = (p < 256);
                #pragma unroll
                for (int nt = 0; nt < 4; ++nt) {
                    int gc = n0w + nt * 16 + l15;
                    float v = acc[mt][nt][reg] + bb[nt];
                    if (hasm) v += mrow[gc];
                    outb[orow + gc] = f2bf(gelu_f(v));
                }
            }
        }
    }

    if constexpr (STAGE == 2) {
        __shared__ float rsum[4][64];
        __shared__ float rsq[4][64];
        __shared__ float rmu[64], rrs[64];
        float bb[4], gg[4], eb[4];
        #pragma unroll
        for (int nt = 0; nt < 4; ++nt) {
            int gc = n0w + nt * 16 + l15;
            bb[nt] = bias[gc]; gg[nt] = lng[gc]; eb[nt] = lnb[gc];
        }
        #pragma unroll
        for (int mt = 0; mt < 4; ++mt)
            #pragma unroll
            for (int nt = 0; nt < 4; ++nt)
                #pragma unroll
                for (int reg = 0; reg < 4; ++reg)
                    acc[mt][nt][reg] += bb[nt];
        #pragma unroll
        for (int mt = 0; mt < 4; ++mt) {
            #pragma unroll
            for (int reg = 0; reg < 4; ++reg) {
                float s = 0.f, s2 = 0.f;
                #pragma unroll
                for (int nt = 0; nt < 4; ++nt) {
                    float v = acc[mt][nt][reg];
                    s += v; s2 += v * v;
                }
                #pragma unroll
                for (int off = 1; off <= 8; off <<= 1) {
                    s += __shfl_xor(s, off);
                    s2 += __shfl_xor(s2, off);
                }
                if (l15 == 0) {
                    int row = mt * 16 + q * 4 + reg;
                    rsum[wid][row] = s; rsq[wid][row] = s2;
                }
            }
        }
        __syncthreads();
        if (tid < 64) {
            float s = rsum[0][tid] + rsum[1][tid] + rsum[2][tid] + rsum[3][tid];
            float s2 = rsq[0][tid] + rsq[1][tid] + rsq[2][tid] + rsq[3][tid];
            float mu = s * (1.f / 256.f);
            float var = s2 * (1.f / 256.f) - mu * mu;
            rmu[tid] = mu;
            rrs[tid] = rsqrtf(var + 1e-5f);
        }
        __syncthreads();
        #pragma unroll
        for (int mt = 0; mt < 4; ++mt) {
            #pragma unroll
            for (int reg = 0; reg < 4; ++reg) {
                int row = mt * 16 + q * 4 + reg;
                int p = m0 + row;
                float mu = rmu[row], rs = rrs[row];
                long orow = ((long)b * CMAX + p) * 256;
                #pragma unroll
                for (int nt = 0; nt < 4; ++nt) {
                    int gc = n0w + nt * 16 + l15;
                    outb[orow + gc] = f2bf((acc[mt][nt][reg] - mu) * rs * gg[nt] + eb[nt]);
                }
            }
        }
    }

    if constexpr (STAGE == 3) {
        __shared__ float rsum[4][64];
        float bb[4], ww[4];
        #pragma unroll
        for (int nt = 0; nt < 4; ++nt) {
            int gc = n0w + nt * 16 + l15;
            bb[nt] = bias[gc]; ww[nt] = w2v[gc];
        }
        #pragma unroll
        for (int mt = 0; mt < 4; ++mt) {
            #pragma unroll
            for (int reg = 0; reg < 4; ++reg) {
                float s = 0.f;
                #pragma unroll
                for (int nt = 0; nt < 4; ++nt)
                    s += gelu_f(acc[mt][nt][reg] + bb[nt]) * ww[nt];
                #pragma unroll
                for (int off = 1; off <= 8; off <<= 1) s += __shfl_xor(s, off);
                if (l15 == 0) rsum[wid][mt * 16 + q * 4 + reg] = s;
            }
        }
        __syncthreads();
        if (tid < 64) {
            int p = m0 + tid;
            if (p < C) {
                float z = rsum[0][tid] + rsum[1][tid] + rsum[2][tid] + rsum[3][tid] + b2s[0];
                float delta = 1.f / (1.f + expf(-z));
                float na = 0.7f * svals[b * 4096 + p] + 0.3f * delta;
                nac[(long)b * CMAX + p] = fminf(fmaxf(na, 0.f), 1.f);
            }
        }
    }
}

// ---------------- rank-256 value via binary search ----------------
__global__ void __launch_bounds__(256) selectT_k(const float* __restrict__ nac,
        const int* __restrict__ cnt, float* __restrict__ T)
{
    __shared__ float v[CMAX];
    __shared__ int cs[256];
    __shared__ float bounds[2];
    int b = blockIdx.x, tid = threadIdx.x;
    int C = min(cnt[b], CMAX);
    for (int i = tid; i < CMAX; i += 256)
        v[i] = (i < C) ? nac[(long)b * CMAX + i] : -1.f;
    if (tid == 0) { bounds[0] = 0.f; bounds[1] = 1.0f; }
    __syncthreads();
    for (int it = 0; it < 30; ++it) {
        float mid = 0.5f * (bounds[0] + bounds[1]);
        int c = 0;
        for (int i = tid; i < CMAX; i += 256) c += (v[i] >= mid) ? 1 : 0;
        cs[tid] = c; __syncthreads();
        for (int s = 128; s; s >>= 1) {
            if (tid < s) cs[tid] += cs[tid + s];
            __syncthreads();
        }
        if (tid == 0) { if (cs[0] >= 256) bounds[0] = mid; else bounds[1] = mid; }
        __syncthreads();
    }
    if (tid == 0) T[b] = bounds[0];
}

// ---------------- compact band rows into a per-batch list ----------------
__global__ void __launch_bounds__(256) bandlist_k(const float* __restrict__ nac,
        const int* __restrict__ cnt, const float* __restrict__ Tarr,
        int* __restrict__ bandlist, int* __restrict__ bandcnt)
{
    int b = blockIdx.y;
    int C = min(cnt[b], CMAX);
    int p = blockIdx.x * 256 + threadIdx.x;
    if (p < C && fabsf(nac[(long)b * CMAX + p] - Tarr[b]) < BAND_EPS) {
        int slot = atomicAdd(&bandcnt[b], 1);
        if (slot < MAXBAND) bandlist[b * MAXBAND + slot] = p;
    }
}

// ---------------- fp32 recompute: 8 band rows per block, coalesced W^T -------
__global__ void __launch_bounds__(256) bandfix_k(
    const float* __restrict__ hid, const int* __restrict__ sidx,
    const float* __restrict__ msgc,
    const float* __restrict__ w1T, const float* __restrict__ su_b1,
    const float* __restrict__ w2T, const float* __restrict__ su_b2,
    const float* __restrict__ ln_g, const float* __restrict__ ln_b,
    const float* __restrict__ auT, const float* __restrict__ au_b1,
    const float* __restrict__ au_w2, const float* __restrict__ au_b2,
    const float* __restrict__ svals,
    const int* __restrict__ bandlist, const int* __restrict__ bandcnt,
    float* __restrict__ nac, unsigned short* __restrict__ NHb)
{
    int b = blockIdx.y;
    int M = min(bandcnt[b], MAXBAND);
    int base = blockIdx.x * 8;
    if (base >= M) return;
    int nact = min(M - base, 8);
    int tid = threadIdx.x;
    int wid = tid >> 6, lane = tid & 63;
    __shared__ float xr[8][256];
    __shared__ float hy[8][256];   // h1, then y, then gelu-dot terms
    __shared__ float nh[8][256];
    __shared__ float muS[8], rsS[8];
    __shared__ int ppS[8];
    if (tid < 8)
        ppS[tid] = (tid < nact) ? bandlist[b * MAXBAND + base + tid] : -1;
    __syncthreads();
    #pragma unroll
    for (int r = 0; r < 8; ++r) {
        int pp = ppS[r];
        xr[r][tid] = (pp >= 0) ? hid[((long)b * 4096 + sidx[b * 4096 + pp]) * 256 + tid] : 0.f;
    }
    __syncthreads();
    int n = tid;
    // ---- su1: acc[r] = sum_k w1T[k][n] * x[r][k] ----
    float acc[8];
    #pragma unroll
    for (int r = 0; r < 8; ++r) acc[r] = 0.f;
    for (int k = 0; k < 256; k += 4) {
        float w0 = w1T[(k + 0) * 256 + n];
        float w1 = w1T[(k + 1) * 256 + n];
        float w2 = w1T[(k + 2) * 256 + n];
        float w3 = w1T[(k + 3) * 256 + n];
        #pragma unroll
        for (int r = 0; r < 8; ++r) {
            float4 xv = *(const float4*)&xr[r][k];
            acc[r] = fmaf(w0, xv.x, acc[r]);
            acc[r] = fmaf(w1, xv.y, acc[r]);
            acc[r] = fmaf(w2, xv.z, acc[r]);
            acc[r] = fmaf(w3, xv.w, acc[r]);
        }
    }
    float b1v = su_b1[n];
    #pragma unroll
    for (int r = 0; r < 8; ++r) {
        int pp = ppS[r];
        float s = acc[r] + b1v;
        if (pp >= 0 && pp < 256) s += msgc[((long)b * 256 + pp) * 256 + n];
        acc[r] = gelu_f(s);
    }
    __syncthreads();
    #pragma unroll
    for (int r = 0; r < 8; ++r) hy[r][n] = acc[r];
    __syncthreads();
    // ---- su2: y[r][n] = sum_k w2T[k][n] * h1[r][k] + b2 ----
    #pragma unroll
    for (int r = 0; r < 8; ++r) acc[r] = 0.f;
    for (int k = 0; k < 256; k += 4) {
        float w0 = w2T[(k + 0) * 256 + n];
        float w1 = w2T[(k + 1) * 256 + n];
        float w2 = w2T[(k + 2) * 256 + n];
        float w3 = w2T[(k + 3) * 256 + n];
        #pragma unroll
        for (int r = 0; r < 8; ++r) {
            float4 hv = *(const float4*)&hy[r][k];
            acc[r] = fmaf(w0, hv.x, acc[r]);
            acc[r] = fmaf(w1, hv.y, acc[r]);
            acc[r] = fmaf(w2, hv.z, acc[r]);
            acc[r] = fmaf(w3, hv.w, acc[r]);
        }
    }
    __syncthreads();   // all reads of h1 done
    float b2v = su_b2[n];
    #pragma unroll
    for (int r = 0; r < 8; ++r) hy[r][n] = acc[r] + b2v;
    __syncthreads();
    // LN stats: wave wid handles rows wid and wid+4
    #pragma unroll
    for (int rr = 0; rr < 2; ++rr) {
        int r = wid + rr * 4;
        float4 yv = *(const float4*)&hy[r][lane * 4];
        float s = yv.x + yv.y + yv.z + yv.w;
        float s2 = yv.x * yv.x + yv.y * yv.y + yv.z * yv.z + yv.w * yv.w;
        #pragma unroll
        for (int off = 32; off >= 1; off >>= 1) {
            s += __shfl_xor(s, off);
            s2 += __shfl_xor(s2, off);
        }
        if (lane == 0) {
            float mu = s * (1.f / 256.f);
            float var = s2 * (1.f / 256.f) - mu * mu;
            muS[r] = mu; rsS[r] = rsqrtf(var + 1e-5f);
        }
    }
    __syncthreads();
    float gv = ln_g[n], ev = ln_b[n];
    #pragma unroll
    for (int r = 0; r < 8; ++r) {
        float o = (hy[r][n] - muS[r]) * rsS[r] * gv + ev;
        nh[r][n] = o;
        if (ppS[r] >= 0) NHb[((long)b * CMAX + ppS[r]) * 256 + n] = f2bf(o);
    }
    __syncthreads();
    // ---- au: acc[r] = sum_k auT[k][n]*x[r][k] + sum_k auT[256+k][n]*nh[r][k] ----
    #pragma unroll
    for (int r = 0; r < 8; ++r) acc[r] = 0.f;
    for (int k = 0; k < 256; k += 4) {
        float w0 = auT[(k + 0) * 256 + n];
        float w1 = auT[(k + 1) * 256 + n];
        float w2 = auT[(k + 2) * 256 + n];
        float w3 = auT[(k + 3) * 256 + n];
        #pragma unroll
        for (int r = 0; r < 8; ++r) {
            float4 xv = *(const float4*)&xr[r][k];
            acc[r] = fmaf(w0, xv.x, acc[r]);
            acc[r] = fmaf(w1, xv.y, acc[r]);
            acc[r] = fmaf(w2, xv.z, acc[r]);
            acc[r] = fmaf(w3, xv.w, acc[r]);
        }
    }
    for (int k = 0; k < 256; k += 4) {
        float w0 = auT[(256 + k + 0) * 256 + n];
        float w1 = auT[(256 + k + 1) * 256 + n];
        float w2 = auT[(256 + k + 2) * 256 + n];
        float w3 = auT[(256 + k + 3) * 256 + n];
        #pragma unroll
        for (int r = 0; r < 8; ++r) {
            float4 hv = *(const float4*)&nh[r][k];
            acc[r] = fmaf(w0, hv.x, acc[r]);
            acc[r] = fmaf(w1, hv.y, acc[r]);
            acc[r] = fmaf(w2, hv.z, acc[r]);
            acc[r] = fmaf(w3, hv.w, acc[r]);
        }
    }
    float ab = au_b1[n], wv2 = au_w2[n];
    __syncthreads();   // nh reads done; reuse hy
    #pragma unroll
    for (int r = 0; r < 8; ++r) hy[r][n] = gelu_f(acc[r] + ab) * wv2;
    __syncthreads();
    #pragma unroll
    for (int rr = 0; rr < 2; ++rr) {
        int r = wid + rr * 4;
        float4 gvv = *(const float4*)&hy[r][lane * 4];
        float s = gvv.x + gvv.y + gvv.z + gvv.w;
        #pragma unroll
        for (int off = 32; off >= 1; off >>= 1) s += __shfl_xor(s, off);
        if (lane == 0 && ppS[r] >= 0) {
            float z = s + au_b2[0];
            float delta = 1.f / (1.f + expf(-z));
            float na = 0.7f * svals[b * 4096 + ppS[r]] + 0.3f * delta;
            nac[(long)b * CMAX + ppS[r]] = fminf(fmaxf(na, 0.f), 1.f);
        }
    }
}

// ---------------- scatter outputs ----------------
__global__ void __launch_bounds__(64) scatter_k(const float* __restrict__ selv,
        const int* __restrict__ selo, const int* __restrict__ selp,
        const unsigned short* __restrict__ NHb, float* __restrict__ out)
{
    int b = blockIdx.x >> 8, j = blockIdx.x & 255, t = threadIdx.x;
    int orig = selo[b * 256 + j];
    int p = selp[b * 256 + j];
    if (t == 0) out[b * 4096 + orig] = selv[b * 256 + j];
    const ushort4* src = (const ushort4*)(NHb + ((long)b * CMAX + p) * 256);
    ushort4 s = src[t];
    float4 o = make_float4(bf2f(s.x), bf2f(s.y), bf2f(s.z), bf2f(s.w));
    *(float4*)(out + 131072 + ((long)(b * 4096 + orig)) * 256 + t * 4) = o;
}

extern "C" void kernel_launch(void* const* d_in, const int* in_sizes, int n_in,
                              void* d_out, int out_size, void* d_ws, size_t ws_size,
                              hipStream_t stream)
{
    const float* act   = (const float*)d_in[0];
    const float* hid   = (const float*)d_in[1];
    const float* wi    = (const float*)d_in[2];
    const float* bi    = (const float*)d_in[3];
    const float* wo    = (const float*)d_in[4];
    const float* bo    = (const float*)d_in[5];
    const float* su_w1 = (const float*)d_in[6];
    const float* su_b1 = (const float*)d_in[7];
    const float* su_w2 = (const float*)d_in[8];
    const float* su_b2 = (const float*)d_in[9];
    const float* au_w1 = (const float*)d_in[10];
    const float* au_b1 = (const float*)d_in[11];
    const float* au_w2 = (const float*)d_in[12];
    const float* au_b2 = (const float*)d_in[13];
    const float* ln_g  = (const float*)d_in[14];
    const float* ln_b  = (const float*)d_in[15];
    float* out = (float*)d_out;

    char* ws = (char*)d_ws;
    size_t off = 0;
    auto alloc = [&](size_t bytes) {
        size_t o = off; off += (bytes + 255) & ~(size_t)255; return o;
    };
    float* svals = (float*)(ws + alloc((size_t)32 * 4096 * 4));
    int*   sidx  = (int*)  (ws + alloc((size_t)32 * 4096 * 4));
    int*   cnt   = (int*)  (ws + alloc(256));
    float* qkv   = (float*)(ws + alloc((size_t)32 * 256 * 768 * 4));
    float* Sb    = (float*)(ws + alloc((size_t)32 * 4 * 256 * 256 * 4));
    float* Ob    = (float*)(ws + alloc((size_t)32 * 256 * 256 * 4));
    float* MSG   = (float*)(ws + alloc((size_t)32 * 256 * 256 * 4));
    float* MSGC  = (float*)(ws + alloc((size_t)32 * 256 * 256 * 4));
    float* selv  = (float*)(ws + alloc((size_t)32 * 256 * 4));
    int*   selo  = (int*)  (ws + alloc((size_t)32 * 256 * 4));
    int*   selp  = (int*)  (ws + alloc((size_t)32 * 256 * 4));
    unsigned short* swb1 = (unsigned short*)(ws + alloc((size_t)256 * 512 * 2));
    unsigned short* swb2 = (unsigned short*)(ws + alloc((size_t)256 * 256 * 2));
    unsigned short* awb1 = (unsigned short*)(ws + alloc((size_t)256 * 512 * 2));
    float* w1T = (float*)(ws + alloc((size_t)256 * 256 * 4));
    float* w2T = (float*)(ws + alloc((size_t)256 * 256 * 4));
    float* auT = (float*)(ws + alloc((size_t)512 * 256 * 4));
    unsigned short* Xb   = (unsigned short*)(ws + alloc((size_t)32 * CMAX * 256 * 2));
    unsigned short* H1b  = (unsigned short*)(ws + alloc((size_t)32 * CMAX * 256 * 2));
    unsigned short* NHb  = (unsigned short*)(ws + alloc((size_t)32 * CMAX * 256 * 2));
    float* nac = (float*)(ws + alloc((size_t)32 * CMAX * 4));
    float* Tb  = (float*)(ws + alloc(128));
    int* bandl = (int*)(ws + alloc((size_t)32 * MAXBAND * 4));
    int* bandc = (int*)(ws + alloc(128));

    // 0. zero band counters
    hipMemsetAsync(bandc, 0, 32 * sizeof(int), stream);
    // 1. zero outputs
    fill0_k<<<2048, 256, 0, stream>>>((float4*)out, (long)out_size / 4);
    // 2. sort activations
    topk1_k<<<32, 256, 0, stream>>>(act, svals, sidx, cnt);
    // 3. weight conversion + fp32 transposes (independent of data)
    convw_k<<<512, 256, 0, stream>>>(su_w1, su_w2, au_w1, swb1, swb2, awb1);
    transT_k<<<dim3(8, 8), 256, 0, stream>>>(su_w1, 512, 0, w1T);
    transT_k<<<dim3(8, 8), 256, 0, stream>>>(su_w2, 256, 0, w2T);
    transT_k<<<dim3(16, 8), 256, 0, stream>>>(au_w1, 512, 0, auT);
    // 4. gather + bf16 candidate rows
    gatherX_k<<<dim3(CMAX / 4, 32), 256, 0, stream>>>(hid, sidx, cnt, Xb);
    // 5. qkv = gather(hidden) @ wi^T + bi
    gemm_k<64, 256, 8, 8, true, true, 1><<<dim3(3, 4, 32), 256, 0, stream>>>(
        hid, 256, (long)4096 * 256, 0, 1,
        wi, 256, 0, 0, 1,
        qkv, 768, (long)256 * 768, 0, 1,
        256, bi, nullptr, 0, sidx, 4096, 0.f);
    // 6. S = q @ k^T / 8
    gemm_k<64, 256, 8, 8, true, false, 3><<<dim3(1, 4, 128), 256, 0, stream>>>(
        qkv, 768, 196608, 64, 4,
        qkv + 256, 768, 196608, 64, 4,
        Sb, 256, 65536, 0, 1,
        64, nullptr, nullptr, 0, nullptr, 0, 0.125f);
    // 7. softmax
    softmax_k<<<8192, 256, 0, stream>>>(Sb);
    // 8. O = P @ V
    gemm_k<64, 64, 4, 4, false, false, 0><<<dim3(1, 4, 128), 256, 0, stream>>>(
        Sb, 256, 65536, 0, 1,
        qkv + 512, 768, 196608, 64, 4,
        Ob, 256, 65536, 64, 4,
        256, nullptr, nullptr, 0, nullptr, 0, 0.f);
    // 9. MSG = (O @ wo^T + bo) * topk_vals
    gemm_k<64, 256, 8, 8, true, false, 2><<<dim3(1, 4, 32), 256, 0, stream>>>(
        Ob, 256, 65536, 0, 1,
        wo, 256, 0, 0, 1,
        MSG, 256, 65536, 0, 1,
        256, bo, svals, 4096, nullptr, 0, 0.f);
    // 10. MSGC = MSG @ W1b^T
    gemm_k<64, 256, 8, 8, true, false, 0><<<dim3(1, 4, 32), 256, 0, stream>>>(
        MSG, 256, 65536, 0, 1,
        su_w1 + 256, 512, 0, 0, 1,
        MSGC, 256, 65536, 0, 1,
        256, nullptr, nullptr, 0, nullptr, 0, 0.f);
    // 11-13. candidate-row MLPs in bf16 MFMA
    dim3 mgrid(CMAX / 64, 32);
    mlp_mfma_k<1><<<mgrid, 256, 0, stream>>>(Xb, nullptr, swb1, 512, su_b1, MSGC,
        nullptr, nullptr, nullptr, nullptr, nullptr, cnt, H1b, nullptr);
    mlp_mfma_k<2><<<mgrid, 256, 0, stream>>>(H1b, nullptr, swb2, 256, su_b2, nullptr,
        ln_g, ln_b, nullptr, nullptr, nullptr, cnt, NHb, nullptr);
    mlp_mfma_k<3><<<mgrid, 256, 0, stream>>>(Xb, NHb, awb1, 512, au_b1, nullptr,
        nullptr, nullptr, au_w2, au_b2, svals, cnt, nullptr, nac);
    // 14. rank-256 value per batch
    selectT_k<<<32, 256, 0, stream>>>(nac, cnt, Tb);
    // 15a. compact band rows
    bandlist_k<<<dim3(CMAX / 256, 32), 256, 0, stream>>>(nac, cnt, Tb, bandl, bandc);
    // 15b. fp32 recompute of boundary-band rows, 8 rows/block, coalesced
    bandfix_k<<<dim3(MAXBAND / 8, 32), 256, 0, stream>>>(hid, sidx, MSGC,
        w1T, su_b1, w2T, su_b2, ln_g, ln_b, auT, au_b1, au_w2, au_b2,
        svals, bandl, bandc, nac, NHb);
    // 16. top-k over corrected new activations
    topk2_k<<<32, 256, 0, stream>>>(nac, sidx, cnt, selv, selo, selp);
    // 17. scatter selected rows
    scatter_k<<<8192, 64, 0, stream>>>(selv, selo, selp, NHb, out);
}

// Round 5
// 831.570 us; speedup vs baseline: 4.1771x; 1.2433x over previous
//
#include <hip/hip_runtime.h>

// NeuronInteraction: B=32, N=4096, D=256, H=4, hd=64, MSG_K=256, k=256
// Pipeline:
//  fill0 -> topk1(radix-select acts) -> convW(bf16 weights) -> transT(fp32 W^T) ->
//  gatherX(bf16 candidate rows) -> fp32 attention chain -> bf16 MFMA MLPs ->
//  selectT -> bandlist -> bandfix (fp32 recompute, 8 rows/block, coalesced W^T)
//  -> topk2(radix-select cands) -> scatter.
// Top-k via exact threshold selection (not sort): MHA is permutation-invariant
// over gathered tokens and outputs are index-scatters, so only the exact SET
// (with lowest-index tie-break, matching jax.lax.top_k) matters.
// Candidate pruning: rows with a < a*(256th) - 3/7 provably can't be selected.

constexpr int KC = 32;
constexpr int CMAX = 2304;           // E[cands]=2012, sigma~32 -> +9 sigma
constexpr float BAND_EPS = 0.01f;    // ~13x bf16-path na error bound
constexpr int MAXBAND = 512;         // E[band]~117 -> huge margin

typedef short bf16x8 __attribute__((ext_vector_type(8)));
typedef float f32x4 __attribute__((ext_vector_type(4)));

__device__ __forceinline__ float gelu_f(float x) {
    return 0.5f * x * (1.0f + erff(x * 0.70710678118654752440f));
}
__device__ __forceinline__ unsigned short f2bf(float f) {
    unsigned u = __float_as_uint(f);
    return (unsigned short)((u + 0x7fffu + ((u >> 16) & 1u)) >> 16);
}
__device__ __forceinline__ float bf2f(unsigned short h) {
    return __uint_as_float(((unsigned)h) << 16);
}

// ---------------- zero-fill output ----------------
__global__ void __launch_bounds__(256) fill0_k(float4* p, long n4) {
    long i = (long)blockIdx.x * 256 + threadIdx.x;
    long stride = (long)gridDim.x * 256;
    float4 z = make_float4(0.f, 0.f, 0.f, 0.f);
    for (; i < n4; i += stride) p[i] = z;
}

// ---------------- top-k #1: radix threshold selection + compaction ----------
// Slots 0..255 = exact top-256 set (jax tie-break: lowest index), slots
// 256..cnt-1 = remaining candidates (a >= a256 - 3/7). Order within groups is
// arbitrary (atomics) — downstream is order-invariant.
__global__ void __launch_bounds__(256) topk1_k(const float* __restrict__ act,
        float* __restrict__ svals, int* __restrict__ sidx, int* __restrict__ cnt)
{
    __shared__ int cs[4];
    __shared__ int sTop, sRest;
    int b = blockIdx.x, tid = threadIdx.x;
    int wid = tid >> 6, lane = tid & 63;
    unsigned v[16];
    #pragma unroll
    for (int s = 0; s < 16; ++s)
        v[s] = __float_as_uint(act[b * 4096 + s * 256 + tid]); // >=0: bits monotone

    auto reduce4 = [&](int c) -> int {
        #pragma unroll
        for (int off = 32; off >= 1; off >>= 1) c += __shfl_xor(c, off);
        if (lane == 0) cs[wid] = c;
        __syncthreads();
        int tot = cs[0] + cs[1] + cs[2] + cs[3];
        __syncthreads();
        return tot;
    };
    auto countGE = [&](unsigned thr) -> int {
        int c = 0;
        #pragma unroll
        for (int s = 0; s < 16; ++s) c += (v[s] >= thr) ? 1 : 0;
        return reduce4(c);
    };
    auto countEqLt = [&](unsigned vs, int icut) -> int {
        int c = 0;
        #pragma unroll
        for (int s = 0; s < 16; ++s)
            c += (v[s] == vs && (s * 256 + tid) < icut) ? 1 : 0;
        return reduce4(c);
    };

    // v* = 256th largest value, built bit-by-bit
    unsigned vstar = 0;
    for (int bit = 31; bit >= 0; --bit) {
        unsigned cand = vstar | (1u << bit);
        if (countGE(cand) >= 256) vstar = cand;
    }
    int cgt = countGE(vstar + 1);          // vstar < bits(1.0): no overflow
    int needed = 256 - cgt;                // >= 1
    int icut = 4096;                       // include ties with idx < icut
    if (countEqLt(vstar, 4096) > needed) {
        int lo = 0, hi = 4096;             // count(lo)<=needed, count(hi)>needed
        for (int it = 0; it < 12; ++it) {
            int mid = (lo + hi) >> 1;
            if (countEqLt(vstar, mid) <= needed) lo = mid; else hi = mid;
        }
        icut = lo;                         // count(idx<icut) == needed exactly
    }
    if (tid == 0) { sTop = 0; sRest = 0; }
    __syncthreads();
    float th = __uint_as_float(vstar) - 0.4288f;  // > 3/7 margin
    #pragma unroll
    for (int s = 0; s < 16; ++s) {
        int i = s * 256 + tid;
        unsigned vb = v[s];
        float f = __uint_as_float(vb);
        bool top = (vb > vstar) || (vb == vstar && i < icut);
        if (top) {
            int slot = atomicAdd(&sTop, 1);
            sidx[b * 4096 + slot] = i;
            svals[b * 4096 + slot] = f;
        } else if (f >= th) {
            int slot = 256 + atomicAdd(&sRest, 1);
            if (slot < CMAX) {
                sidx[b * 4096 + slot] = i;
                svals[b * 4096 + slot] = f;
            }
        }
    }
    __syncthreads();
    if (tid == 0) cnt[b] = min(256 + sRest, CMAX);
}

// ---------------- top-k #2: radix threshold selection over candidates --------
__global__ void __launch_bounds__(256) topk2_k(const float* __restrict__ newact,
        const int* __restrict__ sidx, const int* __restrict__ cnt,
        float* __restrict__ selv, int* __restrict__ selo, int* __restrict__ selp)
{
    __shared__ int cs[4];
    __shared__ int sSel;
    int b = blockIdx.x, tid = threadIdx.x;
    int wid = tid >> 6, lane = tid & 63;
    int C = min(cnt[b], CMAX);
    unsigned v[9];
    int org[9];
    #pragma unroll
    for (int s = 0; s < 9; ++s) {
        int p = s * 256 + tid;
        bool ok = (p < C && p < CMAX);
        v[s] = ok ? __float_as_uint(newact[(long)b * CMAX + p]) : 0u;  // na>0 strictly
        org[s] = ok ? sidx[b * 4096 + p] : 0x7FFFFFFF;
    }
    auto reduce4 = [&](int c) -> int {
        #pragma unroll
        for (int off = 32; off >= 1; off >>= 1) c += __shfl_xor(c, off);
        if (lane == 0) cs[wid] = c;
        __syncthreads();
        int tot = cs[0] + cs[1] + cs[2] + cs[3];
        __syncthreads();
        return tot;
    };
    auto countGE = [&](unsigned thr) -> int {
        int c = 0;
        #pragma unroll
        for (int s = 0; s < 9; ++s) c += (v[s] >= thr) ? 1 : 0;
        return reduce4(c);
    };
    auto countEqLt = [&](unsigned vs, int icut) -> int {
        int c = 0;
        #pragma unroll
        for (int s = 0; s < 9; ++s) c += (v[s] == vs && org[s] < icut) ? 1 : 0;
        return reduce4(c);
    };

    unsigned vstar = 0;
    for (int bit = 31; bit >= 0; --bit) {
        unsigned cand = vstar | (1u << bit);
        if (countGE(cand) >= 256) vstar = cand;
    }
    int cgt = countGE(vstar + 1);
    int needed = 256 - cgt;
    int icut = 4096;                       // tie-break on ORIGINAL index
    if (countEqLt(vstar, 4096) > needed) {
        int lo = 0, hi = 4096;
        for (int it = 0; it < 12; ++it) {
            int mid = (lo + hi) >> 1;
            if (countEqLt(vstar, mid) <= needed) lo = mid; else hi = mid;
        }
        icut = lo;
    }
    if (tid == 0) sSel = 0;
    __syncthreads();
    #pragma unroll
    for (int s = 0; s < 9; ++s) {
        unsigned vb = v[s];
        bool sel = (vb > vstar) || (vb == vstar && org[s] < icut);
        if (sel) {
            int slot = atomicAdd(&sSel, 1);
            selv[b * 256 + slot] = __uint_as_float(vb);
            selo[b * 256 + slot] = org[s];
            selp[b * 256 + slot] = s * 256 + tid;
        }
    }
}

// ---------------- generic fp32 tiled GEMM (attention chain) ----------------
// EPI: 0 none, 1 +bias[n], 2 (+bias[n])*rowscale[m], 3 *cscale
template<int TM, int TN, int RM, int RN, bool BT, bool GATHER, int EPI>
__global__ void __launch_bounds__(256) gemm_k(
    const float* __restrict__ A, int lda, long sA1, long sA2, int divA,
    const float* __restrict__ B, int ldb, long sB1, long sB2, int divB,
    float* __restrict__ C, int ldc, long sC1, long sC2, int divC,
    int K, const float* __restrict__ bias, const float* __restrict__ rowscale,
    long rsStride, const int* __restrict__ gmap, long gmapStride, float cscale)
{
    constexpr int TX = TN / RN, TY = TM / RM;
    static_assert(TX * TY == 256, "block must be 256 threads");
    __shared__ float As[KC][TM + 4];
    __shared__ float Bs[KC][TN + 4];
    int z = blockIdx.z;
    const float* Ab = A + (long)(z / divA) * sA1 + (long)(z % divA) * sA2;
    const float* Bb = B + (long)(z / divB) * sB1 + (long)(z % divB) * sB2;
    float* Cb = C + (long)(z / divC) * sC1 + (long)(z % divC) * sC2;
    int m0 = blockIdx.y * TM, n0 = blockIdx.x * TN;
    int tid = threadIdx.x;
    int tx = tid % TX, ty = tid / TX;
    float acc[RM][RN];
    #pragma unroll
    for (int i = 0; i < RM; ++i)
        #pragma unroll
        for (int j = 0; j < RN; ++j) acc[i][j] = 0.f;

    for (int k0 = 0; k0 < K; k0 += KC) {
        __syncthreads();
        #pragma unroll
        for (int u = 0; u < (TM * KC) / 1024; ++u) {
            int idx = tid + u * 256;
            int m = idx / (KC / 4), k4 = idx % (KC / 4);
            int row = m0 + m;
            long grow = GATHER ? (long)gmap[(long)z * gmapStride + row] : (long)row;
            float4 v = *(const float4*)(Ab + grow * lda + k0 + k4 * 4);
            As[k4 * 4 + 0][m] = v.x; As[k4 * 4 + 1][m] = v.y;
            As[k4 * 4 + 2][m] = v.z; As[k4 * 4 + 3][m] = v.w;
        }
        if (BT) {
            #pragma unroll
            for (int u = 0; u < (TN * KC) / 1024; ++u) {
                int idx = tid + u * 256;
                int n = idx / (KC / 4), k4 = idx % (KC / 4);
                float4 v = *(const float4*)(Bb + (long)(n0 + n) * ldb + k0 + k4 * 4);
                Bs[k4 * 4 + 0][n] = v.x; Bs[k4 * 4 + 1][n] = v.y;
                Bs[k4 * 4 + 2][n] = v.z; Bs[k4 * 4 + 3][n] = v.w;
            }
        } else {
            #pragma unroll
            for (int u = 0; u < (TN * KC) / 1024; ++u) {
                int idx = tid + u * 256;
                int k = idx / (TN / 4), n4 = idx % (TN / 4);
                float4 v = *(const float4*)(Bb + (long)(k0 + k) * ldb + n0 + n4 * 4);
                *(float4*)&Bs[k][n4 * 4] = v;
            }
        }
        __syncthreads();
        #pragma unroll
        for (int k = 0; k < KC; ++k) {
            float av[RM], bv[RN];
            #pragma unroll
            for (int i = 0; i < RM; i += 4) {
                float4 t = *(const float4*)&As[k][ty * RM + i];
                av[i] = t.x; av[i + 1] = t.y; av[i + 2] = t.z; av[i + 3] = t.w;
            }
            #pragma unroll
            for (int j = 0; j < RN; j += 4) {
                float4 t = *(const float4*)&Bs[k][tx * RN + j];
                bv[j] = t.x; bv[j + 1] = t.y; bv[j + 2] = t.z; bv[j + 3] = t.w;
            }
            #pragma unroll
            for (int i = 0; i < RM; ++i)
                #pragma unroll
                for (int j = 0; j < RN; ++j)
                    acc[i][j] = fmaf(av[i], bv[j], acc[i][j]);
        }
    }
    #pragma unroll
    for (int i = 0; i < RM; ++i) {
        int gm = m0 + ty * RM + i;
        float rs = 1.f;
        if (EPI == 2) rs = rowscale[(long)z * rsStride + gm];
        #pragma unroll
        for (int j = 0; j < RN; j += 4) {
            int gn = n0 + tx * RN + j;
            float4 v = make_float4(acc[i][j], acc[i][j + 1], acc[i][j + 2], acc[i][j + 3]);
            if (EPI == 1 || EPI == 2) {
                float4 bb = *(const float4*)(bias + gn);
                v.x += bb.x; v.y += bb.y; v.z += bb.z; v.w += bb.w;
            }
            if (EPI == 2) { v.x *= rs; v.y *= rs; v.z *= rs; v.w *= rs; }
            if (EPI == 3) { v.x *= cscale; v.y *= cscale; v.z *= cscale; v.w *= cscale; }
            *(float4*)(Cb + (long)gm * ldc + gn) = v;
        }
    }
}

// ---------------- softmax over rows of 256 (1 wave / row) ----------------
__global__ void __launch_bounds__(256) softmax_k(float* __restrict__ S) {
    int row = blockIdx.x * 4 + (threadIdx.x >> 6);
    int lane = threadIdx.x & 63;
    float4* r = (float4*)(S + (long)row * 256);
    float4 v = r[lane];
    float m = fmaxf(fmaxf(v.x, v.y), fmaxf(v.z, v.w));
    for (int off = 32; off >= 1; off >>= 1) m = fmaxf(m, __shfl_xor(m, off));
    v.x = expf(v.x - m); v.y = expf(v.y - m); v.z = expf(v.z - m); v.w = expf(v.w - m);
    float s = v.x + v.y + v.z + v.w;
    for (int off = 32; off >= 1; off >>= 1) s += __shfl_xor(s, off);
    float inv = 1.f / s;
    v.x *= inv; v.y *= inv; v.z *= inv; v.w *= inv;
    r[lane] = v;
}

// ---------------- weight fp32->bf16 conversion ----------------
__global__ void __launch_bounds__(256) convw_k(
        const float* __restrict__ s1, const float* __restrict__ s2,
        const float* __restrict__ a1,
        unsigned short* __restrict__ o1, unsigned short* __restrict__ o2,
        unsigned short* __restrict__ o3)
{
    int i = blockIdx.x * 256 + threadIdx.x;   // grid 512 -> 131072
    o1[i] = f2bf(s1[i]);
    o3[i] = f2bf(a1[i]);
    if (i < 65536) o2[i] = f2bf(s2[i]);
}

// ---------------- fp32 weight transpose: dst[k][n] = src[n][koff+k] ----------
__global__ void __launch_bounds__(256) transT_k(const float* __restrict__ src,
        int ld, int koff, float* __restrict__ dst)
{
    __shared__ float t[32][33];
    int k0 = blockIdx.x * 32, n0 = blockIdx.y * 32;
    int tx = threadIdx.x & 31, ty = threadIdx.x >> 5;
    #pragma unroll
    for (int yy = 0; yy < 4; ++yy) {
        int nl = ty * 4 + yy;
        t[nl][tx] = src[(long)(n0 + nl) * ld + koff + k0 + tx];
    }
    __syncthreads();
    #pragma unroll
    for (int yy = 0; yy < 4; ++yy) {
        int kl = ty * 4 + yy;
        dst[(long)(k0 + kl) * 256 + n0 + tx] = t[tx][kl];
    }
}

// ---------------- gather candidate rows -> bf16 [B][CMAX][256] ----------------
__global__ void __launch_bounds__(256) gatherX_k(const float* __restrict__ hid,
        const int* __restrict__ sidx, const int* __restrict__ cnt,
        unsigned short* __restrict__ Xb)
{
    int b = blockIdx.y;
    int C = min(cnt[b], CMAX);
    int p = blockIdx.x * 4 + (threadIdx.x >> 6);
    int lane = threadIdx.x & 63;
    unsigned short* dst = Xb + ((long)b * CMAX + p) * 256 + lane * 4;
    if (p < C) {
        int row = sidx[b * 4096 + p];
        float4 v = *(const float4*)(hid + ((long)b * 4096 + row) * 256 + lane * 4);
        ushort4 o; o.x = f2bf(v.x); o.y = f2bf(v.y); o.z = f2bf(v.z); o.w = f2bf(v.w);
        *(ushort4*)dst = o;
    } else {
        ushort4 z; z.x = 0; z.y = 0; z.z = 0; z.w = 0;
        *(ushort4*)dst = z;
    }
}

// ---------------- bf16 MFMA MLP: block = 64 rows x 256 cols, 4 waves 1x4 ----
template<int STAGE>
__global__ void __launch_bounds__(256, 2) mlp_mfma_k(
    const unsigned short* __restrict__ A0,
    const unsigned short* __restrict__ A1,
    const unsigned short* __restrict__ W, int ldw,
    const float* __restrict__ bias,
    const float* __restrict__ msgc,
    const float* __restrict__ lng, const float* __restrict__ lnb,
    const float* __restrict__ w2v, const float* __restrict__ b2s,
    const float* __restrict__ svals,
    const int* __restrict__ cnt,
    unsigned short* __restrict__ outb,
    float* __restrict__ nac)
{
    int b = blockIdx.y;
    int C = min(cnt[b], CMAX);
    int m0 = blockIdx.x * 64;
    if (m0 >= C) return;
    int tid = threadIdx.x;
    int wid = tid >> 6;
    int lane = tid & 63;
    int l15 = lane & 15;
    int q = lane >> 4;
    int n0w = wid * 64;

    f32x4 acc[4][4];
    #pragma unroll
    for (int mt = 0; mt < 4; ++mt)
        #pragma unroll
        for (int nt = 0; nt < 4; ++nt) {
            f32x4 z = {0.f, 0.f, 0.f, 0.f};
            acc[mt][nt] = z;
        }

    const unsigned short* Ab = A0 + ((long)b * CMAX + m0) * 256;
    const unsigned short* A1b = (STAGE == 3) ? (A1 + ((long)b * CMAX + m0) * 256) : nullptr;
    int aoff[4];
    #pragma unroll
    for (int mt = 0; mt < 4; ++mt) aoff[mt] = (mt * 16 + l15) * 256;
    const unsigned short* wr[4];
    #pragma unroll
    for (int nt = 0; nt < 4; ++nt) wr[nt] = W + (long)(n0w + nt * 16 + l15) * ldw;

    constexpr int KSTEPS = (STAGE == 3) ? 16 : 8;
    #pragma unroll 4
    for (int ks = 0; ks < KSTEPS; ++ks) {
        const unsigned short* As = (STAGE == 3 && ks >= 8) ? A1b : Ab;
        int ko = (STAGE == 3 && ks >= 8) ? (ks - 8) * 32 : ks * 32;
        int kw = ks * 32;
        bf16x8 af[4], bfr[4];
        #pragma unroll
        for (int mt = 0; mt < 4; ++mt)
            af[mt] = *(const bf16x8*)(As + aoff[mt] + ko + q * 8);
        #pragma unroll
        for (int nt = 0; nt < 4; ++nt)
            bfr[nt] = *(const bf16x8*)(wr[nt] + kw + q * 8);
        #pragma unroll
        for (int mt = 0; mt < 4; ++mt)
            #pragma unroll
            for (int nt = 0; nt < 4; ++nt)
                acc[mt][nt] = __builtin_amdgcn_mfma_f32_16x16x32_bf16(
                    af[mt], bfr[nt], acc[mt][nt], 0, 0, 0);
    }

    if constexpr (STAGE == 1) {
        float bb[4];
        #pragma unroll
        for (int nt = 0; nt < 4; ++nt) bb[nt] = bias[n0w + nt * 16 + l15];
        #pragma unroll
        for (int mt = 0; mt < 4; ++mt) {
            #pragma unroll
            for (int reg = 0; reg < 4; ++reg) {
                int p = m0 + mt * 16 + q * 4 + reg;
                long orow = ((long)b * CMAX + p) * 256;
                const float* mrow = msgc + ((long)b * 256 + p) * 256;
                bool hasm = (p < 256);
                #pragma unroll
                for (int nt = 0; nt < 4; ++nt) {
                    int gc = n0w + nt * 16 + l15;
                    float v = acc[mt][nt][reg] + bb[nt];
                    if (hasm) v += mrow[gc];
                    outb[orow + gc] = f2bf(gelu_f(v));
                }
            }
        }
    }

    if constexpr (STAGE == 2) {
        __shared__ float rsum[4][64];
        __shared__ float rsq[4][64];
        __shared__ float rmu[64], rrs[64];
        float bb[4], gg[4], eb[4];
        #pragma unroll
        for (int nt = 0; nt < 4; ++nt) {
            int gc = n0w + nt * 16 + l15;
            bb[nt] = bias[gc]; gg[nt] = lng[gc]; eb[nt] = lnb[gc];
        }
        #pragma unroll
        for (int mt = 0; mt < 4; ++mt)
            #pragma unroll
            for (int nt = 0; nt < 4; ++nt)
                #pragma unroll
                for (int reg = 0; reg < 4; ++reg)
                    acc[mt][nt][reg] += bb[nt];
        #pragma unroll
        for (int mt = 0; mt < 4; ++mt) {
            #pragma unroll
            for (int reg = 0; reg < 4; ++reg) {
                float s = 0.f, s2 = 0.f;
                #pragma unroll
                for (int nt = 0; nt < 4; ++nt) {
                    float v = acc[mt][nt][reg];
                    s += v; s2 += v * v;
                }
                #pragma unroll
                for (int off = 1; off <= 8; off <<= 1) {
                    s += __shfl_xor(s, off);
                    s2 += __shfl_xor(s2, off);
                }
                if (l15 == 0) {
                    int row = mt * 16 + q * 4 + reg;
                    rsum[wid][row] = s; rsq[wid][row] = s2;
                }
            }
        }
        __syncthreads();
        if (tid < 64) {
            float s = rsum[0][tid] + rsum[1][tid] + rsum[2][tid] + rsum[3][tid];
            float s2 = rsq[0][tid] + rsq[1][tid] + rsq[2][tid] + rsq[3][tid];
            float mu = s * (1.f / 256.f);
            float var = s2 * (1.f / 256.f) - mu * mu;
            rmu[tid] = mu;
            rrs[tid] = rsqrtf(var + 1e-5f);
        }
        __syncthreads();
        #pragma unroll
        for (int mt = 0; mt < 4; ++mt) {
            #pragma unroll
            for (int reg = 0; reg < 4; ++reg) {
                int row = mt * 16 + q * 4 + reg;
                int p = m0 + row;
                float mu = rmu[row], rs = rrs[row];
                long orow = ((long)b * CMAX + p) * 256;
                #pragma unroll
                for (int nt = 0; nt < 4; ++nt) {
                    int gc = n0w + nt * 16 + l15;
                    outb[orow + gc] = f2bf((acc[mt][nt][reg] - mu) * rs * gg[nt] + eb[nt]);
                }
            }
        }
    }

    if constexpr (STAGE == 3) {
        __shared__ float rsum[4][64];
        float bb[4], ww[4];
        #pragma unroll
        for (int nt = 0; nt < 4; ++nt) {
            int gc = n0w + nt * 16 + l15;
            bb[nt] = bias[gc]; ww[nt] = w2v[gc];
        }
        #pragma unroll
        for (int mt = 0; mt < 4; ++mt) {
            #pragma unroll
            for (int reg = 0; reg < 4; ++reg) {
                float s = 0.f;
                #pragma unroll
                for (int nt = 0; nt < 4; ++nt)
                    s += gelu_f(acc[mt][nt][reg] + bb[nt]) * ww[nt];
                #pragma unroll
                for (int off = 1; off <= 8; off <<= 1) s += __shfl_xor(s, off);
                if (l15 == 0) rsum[wid][mt * 16 + q * 4 + reg] = s;
            }
        }
        __syncthreads();
        if (tid < 64) {
            int p = m0 + tid;
            if (p < C) {
                float z = rsum[0][tid] + rsum[1][tid] + rsum[2][tid] + rsum[3][tid] + b2s[0];
                float delta = 1.f / (1.f + expf(-z));
                float na = 0.7f * svals[b * 4096 + p] + 0.3f * delta;
                nac[(long)b * CMAX + p] = fminf(fmaxf(na, 0.f), 1.f);
            }
        }
    }
}

// ---------------- rank-256 value via binary search ----------------
__global__ void __launch_bounds__(256) selectT_k(const float* __restrict__ nac,
        const int* __restrict__ cnt, float* __restrict__ T)
{
    __shared__ float v[CMAX];
    __shared__ int cs[256];
    __shared__ float bounds[2];
    int b = blockIdx.x, tid = threadIdx.x;
    int C = min(cnt[b], CMAX);
    for (int i = tid; i < CMAX; i += 256)
        v[i] = (i < C) ? nac[(long)b * CMAX + i] : -1.f;
    if (tid == 0) { bounds[0] = 0.f; bounds[1] = 1.0f; }
    __syncthreads();
    for (int it = 0; it < 30; ++it) {
        float mid = 0.5f * (bounds[0] + bounds[1]);
        int c = 0;
        for (int i = tid; i < CMAX; i += 256) c += (v[i] >= mid) ? 1 : 0;
        cs[tid] = c; __syncthreads();
        for (int s = 128; s; s >>= 1) {
            if (tid < s) cs[tid] += cs[tid + s];
            __syncthreads();
        }
        if (tid == 0) { if (cs[0] >= 256) bounds[0] = mid; else bounds[1] = mid; }
        __syncthreads();
    }
    if (tid == 0) T[b] = bounds[0];
}

// ---------------- compact band rows into a per-batch list ----------------
__global__ void __launch_bounds__(256) bandlist_k(const float* __restrict__ nac,
        const int* __restrict__ cnt, const float* __restrict__ Tarr,
        int* __restrict__ bandlist, int* __restrict__ bandcnt)
{
    int b = blockIdx.y;
    int C = min(cnt[b], CMAX);
    int p = blockIdx.x * 256 + threadIdx.x;
    if (p < C && fabsf(nac[(long)b * CMAX + p] - Tarr[b]) < BAND_EPS) {
        int slot = atomicAdd(&bandcnt[b], 1);
        if (slot < MAXBAND) bandlist[b * MAXBAND + slot] = p;
    }
}

// ---------------- fp32 recompute: 8 band rows per block, coalesced W^T -------
__global__ void __launch_bounds__(256) bandfix_k(
    const float* __restrict__ hid, const int* __restrict__ sidx,
    const float* __restrict__ msgc,
    const float* __restrict__ w1T, const float* __restrict__ su_b1,
    const float* __restrict__ w2T, const float* __restrict__ su_b2,
    const float* __restrict__ ln_g, const float* __restrict__ ln_b,
    const float* __restrict__ auT, const float* __restrict__ au_b1,
    const float* __restrict__ au_w2, const float* __restrict__ au_b2,
    const float* __restrict__ svals,
    const int* __restrict__ bandlist, const int* __restrict__ bandcnt,
    float* __restrict__ nac, unsigned short* __restrict__ NHb)
{
    int b = blockIdx.y;
    int M = min(bandcnt[b], MAXBAND);
    int base = blockIdx.x * 8;
    if (base >= M) return;
    int nact = min(M - base, 8);
    int tid = threadIdx.x;
    int wid = tid >> 6, lane = tid & 63;
    __shared__ float xr[8][256];
    __shared__ float hy[8][256];
    __shared__ float nh[8][256];
    __shared__ float muS[8], rsS[8];
    __shared__ int ppS[8];
    if (tid < 8)
        ppS[tid] = (tid < nact) ? bandlist[b * MAXBAND + base + tid] : -1;
    __syncthreads();
    #pragma unroll
    for (int r = 0; r < 8; ++r) {
        int pp = ppS[r];
        xr[r][tid] = (pp >= 0) ? hid[((long)b * 4096 + sidx[b * 4096 + pp]) * 256 + tid] : 0.f;
    }
    __syncthreads();
    int n = tid;
    float acc[8];
    #pragma unroll
    for (int r = 0; r < 8; ++r) acc[r] = 0.f;
    for (int k = 0; k < 256; k += 4) {
        float w0 = w1T[(k + 0) * 256 + n];
        float w1 = w1T[(k + 1) * 256 + n];
        float w2 = w1T[(k + 2) * 256 + n];
        float w3 = w1T[(k + 3) * 256 + n];
        #pragma unroll
        for (int r = 0; r < 8; ++r) {
            float4 xv = *(const float4*)&xr[r][k];
            acc[r] = fmaf(w0, xv.x, acc[r]);
            acc[r] = fmaf(w1, xv.y, acc[r]);
            acc[r] = fmaf(w2, xv.z, acc[r]);
            acc[r] = fmaf(w3, xv.w, acc[r]);
        }
    }
    float b1v = su_b1[n];
    #pragma unroll
    for (int r = 0; r < 8; ++r) {
        int pp = ppS[r];
        float s = acc[r] + b1v;
        if (pp >= 0 && pp < 256) s += msgc[((long)b * 256 + pp) * 256 + n];
        acc[r] = gelu_f(s);
    }
    __syncthreads();
    #pragma unroll
    for (int r = 0; r < 8; ++r) hy[r][n] = acc[r];
    __syncthreads();
    #pragma unroll
    for (int r = 0; r < 8; ++r) acc[r] = 0.f;
    for (int k = 0; k < 256; k += 4) {
        float w0 = w2T[(k + 0) * 256 + n];
        float w1 = w2T[(k + 1) * 256 + n];
        float w2 = w2T[(k + 2) * 256 + n];
        float w3 = w2T[(k + 3) * 256 + n];
        #pragma unroll
        for (int r = 0; r < 8; ++r) {
            float4 hv = *(const float4*)&hy[r][k];
            acc[r] = fmaf(w0, hv.x, acc[r]);
            acc[r] = fmaf(w1, hv.y, acc[r]);
            acc[r] = fmaf(w2, hv.z, acc[r]);
            acc[r] = fmaf(w3, hv.w, acc[r]);
        }
    }
    __syncthreads();
    float b2v = su_b2[n];
    #pragma unroll
    for (int r = 0; r < 8; ++r) hy[r][n] = acc[r] + b2v;
    __syncthreads();
    #pragma unroll
    for (int rr = 0; rr < 2; ++rr) {
        int r = wid + rr * 4;
        float4 yv = *(const float4*)&hy[r][lane * 4];
        float s = yv.x + yv.y + yv.z + yv.w;
        float s2 = yv.x * yv.x + yv.y * yv.y + yv.z * yv.z + yv.w * yv.w;
        #pragma unroll
        for (int off = 32; off >= 1; off >>= 1) {
            s += __shfl_xor(s, off);
            s2 += __shfl_xor(s2, off);
        }
        if (lane == 0) {
            float mu = s * (1.f / 256.f);
            float var = s2 * (1.f / 256.f) - mu * mu;
            muS[r] = mu; rsS[r] = rsqrtf(var + 1e-5f);
        }
    }
    __syncthreads();
    float gv = ln_g[n], ev = ln_b[n];
    #pragma unroll
    for (int r = 0; r < 8; ++r) {
        float o = (hy[r][n] - muS[r]) * rsS[r] * gv + ev;
        nh[r][n] = o;
        if (ppS[r] >= 0) NHb[((long)b * CMAX + ppS[r]) * 256 + n] = f2bf(o);
    }
    __syncthreads();
    #pragma unroll
    for (int r = 0; r < 8; ++r) acc[r] = 0.f;
    for (int k = 0; k < 256; k += 4) {
        float w0 = auT[(k + 0) * 256 + n];
        float w1 = auT[(k + 1) * 256 + n];
        float w2 = auT[(k + 2) * 256 + n];
        float w3 = auT[(k + 3) * 256 + n];
        #pragma unroll
        for (int r = 0; r < 8; ++r) {
            float4 xv = *(const float4*)&xr[r][k];
            acc[r] = fmaf(w0, xv.x, acc[r]);
            acc[r] = fmaf(w1, xv.y, acc[r]);
            acc[r] = fmaf(w2, xv.z, acc[r]);
            acc[r] = fmaf(w3, xv.w, acc[r]);
        }
    }
    for (int k = 0; k < 256; k += 4) {
        float w0 = auT[(256 + k + 0) * 256 + n];
        float w1 = auT[(256 + k + 1) * 256 + n];
        float w2 = auT[(256 + k + 2) * 256 + n];
        float w3 = auT[(256 + k + 3) * 256 + n];
        #pragma unroll
        for (int r = 0; r < 8; ++r) {
            float4 hv = *(const float4*)&nh[r][k];
            acc[r] = fmaf(w0, hv.x, acc[r]);
            acc[r] = fmaf(w1, hv.y, acc[r]);
            acc[r] = fmaf(w2, hv.z, acc[r]);
            acc[r] = fmaf(w3, hv.w, acc[r]);
        }
    }
    float ab = au_b1[n], wv2 = au_w2[n];
    __syncthreads();
    #pragma unroll
    for (int r = 0; r < 8; ++r) hy[r][n] = gelu_f(acc[r] + ab) * wv2;
    __syncthreads();
    #pragma unroll
    for (int rr = 0; rr < 2; ++rr) {
        int r = wid + rr * 4;
        float4 gvv = *(const float4*)&hy[r][lane * 4];
        float s = gvv.x + gvv.y + gvv.z + gvv.w;
        #pragma unroll
        for (int off = 32; off >= 1; off >>= 1) s += __shfl_xor(s, off);
        if (lane == 0 && ppS[r] >= 0) {
            float z = s + au_b2[0];
            float delta = 1.f / (1.f + expf(-z));
            float na = 0.7f * svals[b * 4096 + ppS[r]] + 0.3f * delta;
            nac[(long)b * CMAX + ppS[r]] = fminf(fmaxf(na, 0.f), 1.f);
        }
    }
}

// ---------------- scatter outputs ----------------
__global__ void __launch_bounds__(64) scatter_k(const float* __restrict__ selv,
        const int* __restrict__ selo, const int* __restrict__ selp,
        const unsigned short* __restrict__ NHb, float* __restrict__ out)
{
    int b = blockIdx.x >> 8, j = blockIdx.x & 255, t = threadIdx.x;
    int orig = selo[b * 256 + j];
    int p = selp[b * 256 + j];
    if (t == 0) out[b * 4096 + orig] = selv[b * 256 + j];
    const ushort4* src = (const ushort4*)(NHb + ((long)b * CMAX + p) * 256);
    ushort4 s = src[t];
    float4 o = make_float4(bf2f(s.x), bf2f(s.y), bf2f(s.z), bf2f(s.w));
    *(float4*)(out + 131072 + ((long)(b * 4096 + orig)) * 256 + t * 4) = o;
}

extern "C" void kernel_launch(void* const* d_in, const int* in_sizes, int n_in,
                              void* d_out, int out_size, void* d_ws, size_t ws_size,
                              hipStream_t stream)
{
    const float* act   = (const float*)d_in[0];
    const float* hid   = (const float*)d_in[1];
    const float* wi    = (const float*)d_in[2];
    const float* bi    = (const float*)d_in[3];
    const float* wo    = (const float*)d_in[4];
    const float* bo    = (const float*)d_in[5];
    const float* su_w1 = (const float*)d_in[6];
    const float* su_b1 = (const float*)d_in[7];
    const float* su_w2 = (const float*)d_in[8];
    const float* su_b2 = (const float*)d_in[9];
    const float* au_w1 = (const float*)d_in[10];
    const float* au_b1 = (const float*)d_in[11];
    const float* au_w2 = (const float*)d_in[12];
    const float* au_b2 = (const float*)d_in[13];
    const float* ln_g  = (const float*)d_in[14];
    const float* ln_b  = (const float*)d_in[15];
    float* out = (float*)d_out;

    char* ws = (char*)d_ws;
    size_t off = 0;
    auto alloc = [&](size_t bytes) {
        size_t o = off; off += (bytes + 255) & ~(size_t)255; return o;
    };
    float* svals = (float*)(ws + alloc((size_t)32 * 4096 * 4));
    int*   sidx  = (int*)  (ws + alloc((size_t)32 * 4096 * 4));
    int*   cnt   = (int*)  (ws + alloc(256));
    float* qkv   = (float*)(ws + alloc((size_t)32 * 256 * 768 * 4));
    float* Sb    = (float*)(ws + alloc((size_t)32 * 4 * 256 * 256 * 4));
    float* Ob    = (float*)(ws + alloc((size_t)32 * 256 * 256 * 4));
    float* MSG   = (float*)(ws + alloc((size_t)32 * 256 * 256 * 4));
    float* MSGC  = (float*)(ws + alloc((size_t)32 * 256 * 256 * 4));
    float* selv  = (float*)(ws + alloc((size_t)32 * 256 * 4));
    int*   selo  = (int*)  (ws + alloc((size_t)32 * 256 * 4));
    int*   selp  = (int*)  (ws + alloc((size_t)32 * 256 * 4));
    unsigned short* swb1 = (unsigned short*)(ws + alloc((size_t)256 * 512 * 2));
    unsigned short* swb2 = (unsigned short*)(ws + alloc((size_t)256 * 256 * 2));
    unsigned short* awb1 = (unsigned short*)(ws + alloc((size_t)256 * 512 * 2));
    float* w1T = (float*)(ws + alloc((size_t)256 * 256 * 4));
    float* w2T = (float*)(ws + alloc((size_t)256 * 256 * 4));
    float* auT = (float*)(ws + alloc((size_t)512 * 256 * 4));
    unsigned short* Xb   = (unsigned short*)(ws + alloc((size_t)32 * CMAX * 256 * 2));
    unsigned short* H1b  = (unsigned short*)(ws + alloc((size_t)32 * CMAX * 256 * 2));
    unsigned short* NHb  = (unsigned short*)(ws + alloc((size_t)32 * CMAX * 256 * 2));
    float* nac = (float*)(ws + alloc((size_t)32 * CMAX * 4));
    float* Tb  = (float*)(ws + alloc(128));
    int* bandl = (int*)(ws + alloc((size_t)32 * MAXBAND * 4));
    int* bandc = (int*)(ws + alloc(128));

    // 0. zero band counters
    hipMemsetAsync(bandc, 0, 32 * sizeof(int), stream);
    // 1. zero outputs
    fill0_k<<<2048, 256, 0, stream>>>((float4*)out, (long)out_size / 4);
    // 2. radix-select activations (top-256 + candidates, compacted)
    topk1_k<<<32, 256, 0, stream>>>(act, svals, sidx, cnt);
    // 3. weight conversion + fp32 transposes (independent of data)
    convw_k<<<512, 256, 0, stream>>>(su_w1, su_w2, au_w1, swb1, swb2, awb1);
    transT_k<<<dim3(8, 8), 256, 0, stream>>>(su_w1, 512, 0, w1T);
    transT_k<<<dim3(8, 8), 256, 0, stream>>>(su_w2, 256, 0, w2T);
    transT_k<<<dim3(16, 8), 256, 0, stream>>>(au_w1, 512, 0, auT);
    // 4. gather + bf16 candidate rows
    gatherX_k<<<dim3(CMAX / 4, 32), 256, 0, stream>>>(hid, sidx, cnt, Xb);
    // 5. qkv = gather(hidden) @ wi^T + bi
    gemm_k<64, 256, 8, 8, true, true, 1><<<dim3(3, 4, 32), 256, 0, stream>>>(
        hid, 256, (long)4096 * 256, 0, 1,
        wi, 256, 0, 0, 1,
        qkv, 768, (long)256 * 768, 0, 1,
        256, bi, nullptr, 0, sidx, 4096, 0.f);
    // 6. S = q @ k^T / 8
    gemm_k<64, 256, 8, 8, true, false, 3><<<dim3(1, 4, 128), 256, 0, stream>>>(
        qkv, 768, 196608, 64, 4,
        qkv + 256, 768, 196608, 64, 4,
        Sb, 256, 65536, 0, 1,
        64, nullptr, nullptr, 0, nullptr, 0, 0.125f);
    // 7. softmax
    softmax_k<<<8192, 256, 0, stream>>>(Sb);
    // 8. O = P @ V
    gemm_k<64, 64, 4, 4, false, false, 0><<<dim3(1, 4, 128), 256, 0, stream>>>(
        Sb, 256, 65536, 0, 1,
        qkv + 512, 768, 196608, 64, 4,
        Ob, 256, 65536, 64, 4,
        256, nullptr, nullptr, 0, nullptr, 0, 0.f);
    // 9. MSG = (O @ wo^T + bo) * topk_vals
    gemm_k<64, 256, 8, 8, true, false, 2><<<dim3(1, 4, 32), 256, 0, stream>>>(
        Ob, 256, 65536, 0, 1,
        wo, 256, 0, 0, 1,
        MSG, 256, 65536, 0, 1,
        256, bo, svals, 4096, nullptr, 0, 0.f);
    // 10. MSGC = MSG @ W1b^T
    gemm_k<64, 256, 8, 8, true, false, 0><<<dim3(1, 4, 32), 256, 0, stream>>>(
        MSG, 256, 65536, 0, 1,
        su_w1 + 256, 512, 0, 0, 1,
        MSGC, 256, 65536, 0, 1,
        256, nullptr, nullptr, 0, nullptr, 0, 0.f);
    // 11-13. candidate-row MLPs in bf16 MFMA
    dim3 mgrid(CMAX / 64, 32);
    mlp_mfma_k<1><<<mgrid, 256, 0, stream>>>(Xb, nullptr, swb1, 512, su_b1, MSGC,
        nullptr, nullptr, nullptr, nullptr, nullptr, cnt, H1b, nullptr);
    mlp_mfma_k<2><<<mgrid, 256, 0, stream>>>(H1b, nullptr, swb2, 256, su_b2, nullptr,
        ln_g, ln_b, nullptr, nullptr, nullptr, cnt, NHb, nullptr);
    mlp_mfma_k<3><<<mgrid, 256, 0, stream>>>(Xb, NHb, awb1, 512, au_b1, nullptr,
        nullptr, nullptr, au_w2, au_b2, svals, cnt, nullptr, nac);
    // 14. rank-256 value per batch (band center)
    selectT_k<<<32, 256, 0, stream>>>(nac, cnt, Tb);
    // 15a. compact band rows
    bandlist_k<<<dim3(CMAX / 256, 32), 256, 0, stream>>>(nac, cnt, Tb, bandl, bandc);
    // 15b. fp32 recompute of boundary-band rows, 8 rows/block, coalesced
    bandfix_k<<<dim3(MAXBAND / 8, 32), 256, 0, stream>>>(hid, sidx, MSGC,
        w1T, su_b1, w2T, su_b2, ln_g, ln_b, auT, au_b1, au_w2, au_b2,
        svals, bandl, bandc, nac, NHb);
    // 16. exact top-256 selection over corrected new activations
    topk2_k<<<32, 256, 0, stream>>>(nac, sidx, cnt, selv, selo, selp);
    // 17. scatter selected rows
    scatter_k<<<8192, 64, 0, stream>>>(selv, selo, selp, NHb, out);
}

// Round 6
// 795.045 us; speedup vs baseline: 4.3690x; 1.0459x over previous
//
#include <hip/hip_runtime.h>

// NeuronInteraction: B=32, N=4096, D=256, H=4, hd=64, MSG_K=256, k=256
// Pipeline:
//  fill0 -> topk1(radix-select acts) -> prep(bf16 weights + packed W^T) ->
//  gatherX(bf16 candidate rows) -> fp32 attention chain -> bf16 MFMA MLPs ->
//  selectT -> bandlist -> bandfix (fp32 recompute, 4 rows/block, float4 W^T)
//  -> topk2(radix-select cands) -> scatter.
// Top-k via exact threshold selection (not sort): downstream is order-invariant.
// Candidate pruning: rows with a < a*(256th) - 3/7 provably can't be selected.
// BAND_EPS=0.004: bf16-path na error max-stat ~1.1e-4 (36x margin).

constexpr int KC = 32;
constexpr int CMAX = 2304;           // E[cands]=2012, sigma~32 -> +9 sigma
constexpr float BAND_EPS = 0.004f;
constexpr int MAXBAND = 512;         // E[band]~47 -> 10x margin

typedef short bf16x8 __attribute__((ext_vector_type(8)));
typedef float f32x4 __attribute__((ext_vector_type(4)));

__device__ __forceinline__ float gelu_f(float x) {
    return 0.5f * x * (1.0f + erff(x * 0.70710678118654752440f));
}
__device__ __forceinline__ unsigned short f2bf(float f) {
    unsigned u = __float_as_uint(f);
    return (unsigned short)((u + 0x7fffu + ((u >> 16) & 1u)) >> 16);
}
__device__ __forceinline__ float bf2f(unsigned short h) {
    return __uint_as_float(((unsigned)h) << 16);
}

// ---------------- zero-fill output ----------------
__global__ void __launch_bounds__(256) fill0_k(float4* p, long n4) {
    long i = (long)blockIdx.x * 256 + threadIdx.x;
    long stride = (long)gridDim.x * 256;
    float4 z = make_float4(0.f, 0.f, 0.f, 0.f);
    for (; i < n4; i += stride) p[i] = z;
}

// ---------------- top-k #1: radix threshold selection + compaction ----------
__global__ void __launch_bounds__(256) topk1_k(const float* __restrict__ act,
        float* __restrict__ svals, int* __restrict__ sidx, int* __restrict__ cnt)
{
    __shared__ int cs[4];
    __shared__ int sTop, sRest;
    int b = blockIdx.x, tid = threadIdx.x;
    int wid = tid >> 6, lane = tid & 63;
    unsigned v[16];
    #pragma unroll
    for (int s = 0; s < 16; ++s)
        v[s] = __float_as_uint(act[b * 4096 + s * 256 + tid]); // >=0: bits monotone

    auto reduce4 = [&](int c) -> int {
        #pragma unroll
        for (int off = 32; off >= 1; off >>= 1) c += __shfl_xor(c, off);
        if (lane == 0) cs[wid] = c;
        __syncthreads();
        int tot = cs[0] + cs[1] + cs[2] + cs[3];
        __syncthreads();
        return tot;
    };
    auto countGE = [&](unsigned thr) -> int {
        int c = 0;
        #pragma unroll
        for (int s = 0; s < 16; ++s) c += (v[s] >= thr) ? 1 : 0;
        return reduce4(c);
    };
    auto countEqLt = [&](unsigned vs, int icut) -> int {
        int c = 0;
        #pragma unroll
        for (int s = 0; s < 16; ++s)
            c += (v[s] == vs && (s * 256 + tid) < icut) ? 1 : 0;
        return reduce4(c);
    };

    unsigned vstar = 0;
    for (int bit = 31; bit >= 0; --bit) {
        unsigned cand = vstar | (1u << bit);
        if (countGE(cand) >= 256) vstar = cand;
    }
    int cgt = countGE(vstar + 1);
    int needed = 256 - cgt;
    int icut = 4096;
    if (countEqLt(vstar, 4096) > needed) {
        int lo = 0, hi = 4096;
        for (int it = 0; it < 12; ++it) {
            int mid = (lo + hi) >> 1;
            if (countEqLt(vstar, mid) <= needed) lo = mid; else hi = mid;
        }
        icut = lo;
    }
    if (tid == 0) { sTop = 0; sRest = 0; }
    __syncthreads();
    float th = __uint_as_float(vstar) - 0.4288f;  // > 3/7 margin
    #pragma unroll
    for (int s = 0; s < 16; ++s) {
        int i = s * 256 + tid;
        unsigned vb = v[s];
        float f = __uint_as_float(vb);
        bool top = (vb > vstar) || (vb == vstar && i < icut);
        if (top) {
            int slot = atomicAdd(&sTop, 1);
            sidx[b * 4096 + slot] = i;
            svals[b * 4096 + slot] = f;
        } else if (f >= th) {
            int slot = 256 + atomicAdd(&sRest, 1);
            if (slot < CMAX) {
                sidx[b * 4096 + slot] = i;
                svals[b * 4096 + slot] = f;
            }
        }
    }
    __syncthreads();
    if (tid == 0) cnt[b] = min(256 + sRest, CMAX);
}

// ---------------- top-k #2: radix threshold selection over candidates --------
__global__ void __launch_bounds__(256) topk2_k(const float* __restrict__ newact,
        const int* __restrict__ sidx, const int* __restrict__ cnt,
        float* __restrict__ selv, int* __restrict__ selo, int* __restrict__ selp)
{
    __shared__ int cs[4];
    __shared__ int sSel;
    int b = blockIdx.x, tid = threadIdx.x;
    int wid = tid >> 6, lane = tid & 63;
    int C = min(cnt[b], CMAX);
    unsigned v[9];
    int org[9];
    #pragma unroll
    for (int s = 0; s < 9; ++s) {
        int p = s * 256 + tid;
        bool ok = (p < C && p < CMAX);
        v[s] = ok ? __float_as_uint(newact[(long)b * CMAX + p]) : 0u;
        org[s] = ok ? sidx[b * 4096 + p] : 0x7FFFFFFF;
    }
    auto reduce4 = [&](int c) -> int {
        #pragma unroll
        for (int off = 32; off >= 1; off >>= 1) c += __shfl_xor(c, off);
        if (lane == 0) cs[wid] = c;
        __syncthreads();
        int tot = cs[0] + cs[1] + cs[2] + cs[3];
        __syncthreads();
        return tot;
    };
    auto countGE = [&](unsigned thr) -> int {
        int c = 0;
        #pragma unroll
        for (int s = 0; s < 9; ++s) c += (v[s] >= thr) ? 1 : 0;
        return reduce4(c);
    };
    auto countEqLt = [&](unsigned vs, int icut) -> int {
        int c = 0;
        #pragma unroll
        for (int s = 0; s < 9; ++s) c += (v[s] == vs && org[s] < icut) ? 1 : 0;
        return reduce4(c);
    };

    unsigned vstar = 0;
    for (int bit = 31; bit >= 0; --bit) {
        unsigned cand = vstar | (1u << bit);
        if (countGE(cand) >= 256) vstar = cand;
    }
    int cgt = countGE(vstar + 1);
    int needed = 256 - cgt;
    int icut = 4096;
    if (countEqLt(vstar, 4096) > needed) {
        int lo = 0, hi = 4096;
        for (int it = 0; it < 12; ++it) {
            int mid = (lo + hi) >> 1;
            if (countEqLt(vstar, mid) <= needed) lo = mid; else hi = mid;
        }
        icut = lo;
    }
    if (tid == 0) sSel = 0;
    __syncthreads();
    #pragma unroll
    for (int s = 0; s < 9; ++s) {
        unsigned vb = v[s];
        bool sel = (vb > vstar) || (vb == vstar && org[s] < icut);
        if (sel) {
            int slot = atomicAdd(&sSel, 1);
            selv[b * 256 + slot] = __uint_as_float(vb);
            selo[b * 256 + slot] = org[s];
            selp[b * 256 + slot] = s * 256 + tid;
        }
    }
}

// ---------------- generic fp32 tiled GEMM (attention chain) ----------------
template<int TM, int TN, int RM, int RN, bool BT, bool GATHER, int EPI>
__global__ void __launch_bounds__(256) gemm_k(
    const float* __restrict__ A, int lda, long sA1, long sA2, int divA,
    const float* __restrict__ B, int ldb, long sB1, long sB2, int divB,
    float* __restrict__ C, int ldc, long sC1, long sC2, int divC,
    int K, const float* __restrict__ bias, const float* __restrict__ rowscale,
    long rsStride, const int* __restrict__ gmap, long gmapStride, float cscale)
{
    constexpr int TX = TN / RN, TY = TM / RM;
    static_assert(TX * TY == 256, "block must be 256 threads");
    __shared__ float As[KC][TM + 4];
    __shared__ float Bs[KC][TN + 4];
    int z = blockIdx.z;
    const float* Ab = A + (long)(z / divA) * sA1 + (long)(z % divA) * sA2;
    const float* Bb = B + (long)(z / divB) * sB1 + (long)(z % divB) * sB2;
    float* Cb = C + (long)(z / divC) * sC1 + (long)(z % divC) * sC2;
    int m0 = blockIdx.y * TM, n0 = blockIdx.x * TN;
    int tid = threadIdx.x;
    int tx = tid % TX, ty = tid / TX;
    float acc[RM][RN];
    #pragma unroll
    for (int i = 0; i < RM; ++i)
        #pragma unroll
        for (int j = 0; j < RN; ++j) acc[i][j] = 0.f;

    for (int k0 = 0; k0 < K; k0 += KC) {
        __syncthreads();
        #pragma unroll
        for (int u = 0; u < (TM * KC) / 1024; ++u) {
            int idx = tid + u * 256;
            int m = idx / (KC / 4), k4 = idx % (KC / 4);
            int row = m0 + m;
            long grow = GATHER ? (long)gmap[(long)z * gmapStride + row] : (long)row;
            float4 v = *(const float4*)(Ab + grow * lda + k0 + k4 * 4);
            As[k4 * 4 + 0][m] = v.x; As[k4 * 4 + 1][m] = v.y;
            As[k4 * 4 + 2][m] = v.z; As[k4 * 4 + 3][m] = v.w;
        }
        if (BT) {
            #pragma unroll
            for (int u = 0; u < (TN * KC) / 1024; ++u) {
                int idx = tid + u * 256;
                int n = idx / (KC / 4), k4 = idx % (KC / 4);
                float4 v = *(const float4*)(Bb + (long)(n0 + n) * ldb + k0 + k4 * 4);
                Bs[k4 * 4 + 0][n] = v.x; Bs[k4 * 4 + 1][n] = v.y;
                Bs[k4 * 4 + 2][n] = v.z; Bs[k4 * 4 + 3][n] = v.w;
            }
        } else {
            #pragma unroll
            for (int u = 0; u < (TN * KC) / 1024; ++u) {
                int idx = tid + u * 256;
                int k = idx / (TN / 4), n4 = idx % (TN / 4);
                float4 v = *(const float4*)(Bb + (long)(k0 + k) * ldb + n0 + n4 * 4);
                *(float4*)&Bs[k][n4 * 4] = v;
            }
        }
        __syncthreads();
        #pragma unroll
        for (int k = 0; k < KC; ++k) {
            float av[RM], bv[RN];
            #pragma unroll
            for (int i = 0; i < RM; i += 4) {
                float4 t = *(const float4*)&As[k][ty * RM + i];
                av[i] = t.x; av[i + 1] = t.y; av[i + 2] = t.z; av[i + 3] = t.w;
            }
            #pragma unroll
            for (int j = 0; j < RN; j += 4) {
                float4 t = *(const float4*)&Bs[k][tx * RN + j];
                bv[j] = t.x; bv[j + 1] = t.y; bv[j + 2] = t.z; bv[j + 3] = t.w;
            }
            #pragma unroll
            for (int i = 0; i < RM; ++i)
                #pragma unroll
                for (int j = 0; j < RN; ++j)
                    acc[i][j] = fmaf(av[i], bv[j], acc[i][j]);
        }
    }
    #pragma unroll
    for (int i = 0; i < RM; ++i) {
        int gm = m0 + ty * RM + i;
        float rs = 1.f;
        if (EPI == 2) rs = rowscale[(long)z * rsStride + gm];
        #pragma unroll
        for (int j = 0; j < RN; j += 4) {
            int gn = n0 + tx * RN + j;
            float4 v = make_float4(acc[i][j], acc[i][j + 1], acc[i][j + 2], acc[i][j + 3]);
            if (EPI == 1 || EPI == 2) {
                float4 bb = *(const float4*)(bias + gn);
                v.x += bb.x; v.y += bb.y; v.z += bb.z; v.w += bb.w;
            }
            if (EPI == 2) { v.x *= rs; v.y *= rs; v.z *= rs; v.w *= rs; }
            if (EPI == 3) { v.x *= cscale; v.y *= cscale; v.z *= cscale; v.w *= cscale; }
            *(float4*)(Cb + (long)gm * ldc + gn) = v;
        }
    }
}

// ---------------- softmax over rows of 256 (1 wave / row) ----------------
__global__ void __launch_bounds__(256) softmax_k(float* __restrict__ S) {
    int row = blockIdx.x * 4 + (threadIdx.x >> 6);
    int lane = threadIdx.x & 63;
    float4* r = (float4*)(S + (long)row * 256);
    float4 v = r[lane];
    float m = fmaxf(fmaxf(v.x, v.y), fmaxf(v.z, v.w));
    for (int off = 32; off >= 1; off >>= 1) m = fmaxf(m, __shfl_xor(m, off));
    v.x = expf(v.x - m); v.y = expf(v.y - m); v.z = expf(v.z - m); v.w = expf(v.w - m);
    float s = v.x + v.y + v.z + v.w;
    for (int off = 32; off >= 1; off >>= 1) s += __shfl_xor(s, off);
    float inv = 1.f / s;
    v.x *= inv; v.y *= inv; v.z *= inv; v.w *= inv;
    r[lane] = v;
}

// ---------------- prep: bf16 weight conversion + packed fp32 transposes ------
// blocks 0..511: bf16 convert. 512..575: w1P, 576..639: w2P, 640..767: auP.
// Packed layout: dst float4 index (k>>2)*256 + n holds w[k..k+3][n].
__global__ void __launch_bounds__(256) prep_k(
        const float* __restrict__ s1, const float* __restrict__ s2,
        const float* __restrict__ a1,
        unsigned short* __restrict__ o1, unsigned short* __restrict__ o2,
        unsigned short* __restrict__ o3,
        float* __restrict__ w1P, float* __restrict__ w2P, float* __restrict__ auP)
{
    int blk = blockIdx.x, tid = threadIdx.x;
    if (blk < 512) {
        int i = blk * 256 + tid;
        o1[i] = f2bf(s1[i]);
        o3[i] = f2bf(a1[i]);
        if (i < 65536) o2[i] = f2bf(s2[i]);
        return;
    }
    const float* src; float* dst; int ld, ktiles, rel;
    if (blk < 576) { rel = blk - 512; src = s1; ld = 512; dst = w1P; ktiles = 8; }
    else if (blk < 640) { rel = blk - 576; src = s2; ld = 256; dst = w2P; ktiles = 8; }
    else { rel = blk - 640; src = a1; ld = 512; dst = auP; ktiles = 16; }
    int k0 = (rel % ktiles) * 32, n0 = (rel / ktiles) * 32;
    __shared__ float t[32][33];
    int tx = tid & 31, ty = tid >> 5;
    #pragma unroll
    for (int yy = 0; yy < 4; ++yy) {
        int nl = ty * 4 + yy;
        t[nl][tx] = src[(long)(n0 + nl) * ld + k0 + tx];
    }
    __syncthreads();
    #pragma unroll
    for (int yy = 0; yy < 4; ++yy) {
        int k = k0 + ty * 4 + yy;
        dst[(long)(k >> 2) * 1024 + (n0 + tx) * 4 + (k & 3)] = t[tx][ty * 4 + yy];
    }
}

// ---------------- gather candidate rows -> bf16 [B][CMAX][256] ----------------
__global__ void __launch_bounds__(256) gatherX_k(const float* __restrict__ hid,
        const int* __restrict__ sidx, const int* __restrict__ cnt,
        unsigned short* __restrict__ Xb)
{
    int b = blockIdx.y;
    int C = min(cnt[b], CMAX);
    int p = blockIdx.x * 4 + (threadIdx.x >> 6);
    int lane = threadIdx.x & 63;
    unsigned short* dst = Xb + ((long)b * CMAX + p) * 256 + lane * 4;
    if (p < C) {
        int row = sidx[b * 4096 + p];
        float4 v = *(const float4*)(hid + ((long)b * 4096 + row) * 256 + lane * 4);
        ushort4 o; o.x = f2bf(v.x); o.y = f2bf(v.y); o.z = f2bf(v.z); o.w = f2bf(v.w);
        *(ushort4*)dst = o;
    } else {
        ushort4 z; z.x = 0; z.y = 0; z.z = 0; z.w = 0;
        *(ushort4*)dst = z;
    }
}

// ---------------- bf16 MFMA MLP: block = 64 rows x 256 cols, 4 waves 1x4 ----
template<int STAGE>
__global__ void __launch_bounds__(256, 2) mlp_mfma_k(
    const unsigned short* __restrict__ A0,
    const unsigned short* __restrict__ A1,
    const unsigned short* __restrict__ W, int ldw,
    const float* __restrict__ bias,
    const float* __restrict__ msgc,
    const float* __restrict__ lng, const float* __restrict__ lnb,
    const float* __restrict__ w2v, const float* __restrict__ b2s,
    const float* __restrict__ svals,
    const int* __restrict__ cnt,
    unsigned short* __restrict__ outb,
    float* __restrict__ nac)
{
    int b = blockIdx.y;
    int C = min(cnt[b], CMAX);
    int m0 = blockIdx.x * 64;
    if (m0 >= C) return;
    int tid = threadIdx.x;
    int wid = tid >> 6;
    int lane = tid & 63;
    int l15 = lane & 15;
    int q = lane >> 4;
    int n0w = wid * 64;

    f32x4 acc[4][4];
    #pragma unroll
    for (int mt = 0; mt < 4; ++mt)
        #pragma unroll
        for (int nt = 0; nt < 4; ++nt) {
            f32x4 z = {0.f, 0.f, 0.f, 0.f};
            acc[mt][nt] = z;
        }

    const unsigned short* Ab = A0 + ((long)b * CMAX + m0) * 256;
    const unsigned short* A1b = (STAGE == 3) ? (A1 + ((long)b * CMAX + m0) * 256) : nullptr;
    int aoff[4];
    #pragma unroll
    for (int mt = 0; mt < 4; ++mt) aoff[mt] = (mt * 16 + l15) * 256;
    const unsigned short* wr[4];
    #pragma unroll
    for (int nt = 0; nt < 4; ++nt) wr[nt] = W + (long)(n0w + nt * 16 + l15) * ldw;

    constexpr int KSTEPS = (STAGE == 3) ? 16 : 8;
    #pragma unroll 4
    for (int ks = 0; ks < KSTEPS; ++ks) {
        const unsigned short* As = (STAGE == 3 && ks >= 8) ? A1b : Ab;
        int ko = (STAGE == 3 && ks >= 8) ? (ks - 8) * 32 : ks * 32;
        int kw = ks * 32;
        bf16x8 af[4], bfr[4];
        #pragma unroll
        for (int mt = 0; mt < 4; ++mt)
            af[mt] = *(const bf16x8*)(As + aoff[mt] + ko + q * 8);
        #pragma unroll
        for (int nt = 0; nt < 4; ++nt)
            bfr[nt] = *(const bf16x8*)(wr[nt] + kw + q * 8);
        #pragma unroll
        for (int mt = 0; mt < 4; ++mt)
            #pragma unroll
            for (int nt = 0; nt < 4; ++nt)
                acc[mt][nt] = __builtin_amdgcn_mfma_f32_16x16x32_bf16(
                    af[mt], bfr[nt], acc[mt][nt], 0, 0, 0);
    }

    if constexpr (STAGE == 1) {
        float bb[4];
        #pragma unroll
        for (int nt = 0; nt < 4; ++nt) bb[nt] = bias[n0w + nt * 16 + l15];
        #pragma unroll
        for (int mt = 0; mt < 4; ++mt) {
            #pragma unroll
            for (int reg = 0; reg < 4; ++reg) {
                int p = m0 + mt * 16 + q * 4 + reg;
                long orow = ((long)b * CMAX + p) * 256;
                const float* mrow = msgc + ((long)b * 256 + p) * 256;
                bool hasm = (p < 256);
                #pragma unroll
                for (int nt = 0; nt < 4; ++nt) {
                    int gc = n0w + nt * 16 + l15;
                    float v = acc[mt][nt][reg] + bb[nt];
                    if (hasm) v += mrow[gc];
                    outb[orow + gc] = f2bf(gelu_f(v));
                }
            }
        }
    }

    if constexpr (STAGE == 2) {
        __shared__ float rsum[4][64];
        __shared__ float rsq[4][64];
        __shared__ float rmu[64], rrs[64];
        float bb[4], gg[4], eb[4];
        #pragma unroll
        for (int nt = 0; nt < 4; ++nt) {
            int gc = n0w + nt * 16 + l15;
            bb[nt] = bias[gc]; gg[nt] = lng[gc]; eb[nt] = lnb[gc];
        }
        #pragma unroll
        for (int mt = 0; mt < 4; ++mt)
            #pragma unroll
            for (int nt = 0; nt < 4; ++nt)
                #pragma unroll
                for (int reg = 0; reg < 4; ++reg)
                    acc[mt][nt][reg] += bb[nt];
        #pragma unroll
        for (int mt = 0; mt < 4; ++mt) {
            #pragma unroll
            for (int reg = 0; reg < 4; ++reg) {
                float s = 0.f, s2 = 0.f;
                #pragma unroll
                for (int nt = 0; nt < 4; ++nt) {
                    float v = acc[mt][nt][reg];
                    s += v; s2 += v * v;
                }
                #pragma unroll
                for (int off = 1; off <= 8; off <<= 1) {
                    s += __shfl_xor(s, off);
                    s2 += __shfl_xor(s2, off);
                }
                if (l15 == 0) {
                    int row = mt * 16 + q * 4 + reg;
                    rsum[wid][row] = s; rsq[wid][row] = s2;
                }
            }
        }
        __syncthreads();
        if (tid < 64) {
            float s = rsum[0][tid] + rsum[1][tid] + rsum[2][tid] + rsum[3][tid];
            float s2 = rsq[0][tid] + rsq[1][tid] + rsq[2][tid] + rsq[3][tid];
            float mu = s * (1.f / 256.f);
            float var = s2 * (1.f / 256.f) - mu * mu;
            rmu[tid] = mu;
            rrs[tid] = rsqrtf(var + 1e-5f);
        }
        __syncthreads();
        #pragma unroll
        for (int mt = 0; mt < 4; ++mt) {
            #pragma unroll
            for (int reg = 0; reg < 4; ++reg) {
                int row = mt * 16 + q * 4 + reg;
                int p = m0 + row;
                float mu = rmu[row], rs = rrs[row];
                long orow = ((long)b * CMAX + p) * 256;
                #pragma unroll
                for (int nt = 0; nt < 4; ++nt) {
                    int gc = n0w + nt * 16 + l15;
                    outb[orow + gc] = f2bf((acc[mt][nt][reg] - mu) * rs * gg[nt] + eb[nt]);
                }
            }
        }
    }

    if constexpr (STAGE == 3) {
        __shared__ float rsum[4][64];
        float bb[4], ww[4];
        #pragma unroll
        for (int nt = 0; nt < 4; ++nt) {
            int gc = n0w + nt * 16 + l15;
            bb[nt] = bias[gc]; ww[nt] = w2v[gc];
        }
        #pragma unroll
        for (int mt = 0; mt < 4; ++mt) {
            #pragma unroll
            for (int reg = 0; reg < 4; ++reg) {
                float s = 0.f;
                #pragma unroll
                for (int nt = 0; nt < 4; ++nt)
                    s += gelu_f(acc[mt][nt][reg] + bb[nt]) * ww[nt];
                #pragma unroll
                for (int off = 1; off <= 8; off <<= 1) s += __shfl_xor(s, off);
                if (l15 == 0) rsum[wid][mt * 16 + q * 4 + reg] = s;
            }
        }
        __syncthreads();
        if (tid < 64) {
            int p = m0 + tid;
            if (p < C) {
                float z = rsum[0][tid] + rsum[1][tid] + rsum[2][tid] + rsum[3][tid] + b2s[0];
                float delta = 1.f / (1.f + expf(-z));
                float na = 0.7f * svals[b * 4096 + p] + 0.3f * delta;
                nac[(long)b * CMAX + p] = fminf(fmaxf(na, 0.f), 1.f);
            }
        }
    }
}

// ---------------- rank-256 value via binary search ----------------
__global__ void __launch_bounds__(256) selectT_k(const float* __restrict__ nac,
        const int* __restrict__ cnt, float* __restrict__ T)
{
    __shared__ float v[CMAX];
    __shared__ int cs[256];
    __shared__ float bounds[2];
    int b = blockIdx.x, tid = threadIdx.x;
    int C = min(cnt[b], CMAX);
    for (int i = tid; i < CMAX; i += 256)
        v[i] = (i < C) ? nac[(long)b * CMAX + i] : -1.f;
    if (tid == 0) { bounds[0] = 0.f; bounds[1] = 1.0f; }
    __syncthreads();
    for (int it = 0; it < 20; ++it) {   // 1e-6 resolution << BAND_EPS
        float mid = 0.5f * (bounds[0] + bounds[1]);
        int c = 0;
        for (int i = tid; i < CMAX; i += 256) c += (v[i] >= mid) ? 1 : 0;
        cs[tid] = c; __syncthreads();
        for (int s = 128; s; s >>= 1) {
            if (tid < s) cs[tid] += cs[tid + s];
            __syncthreads();
        }
        if (tid == 0) { if (cs[0] >= 256) bounds[0] = mid; else bounds[1] = mid; }
        __syncthreads();
    }
    if (tid == 0) T[b] = bounds[0];
}

// ---------------- compact band rows into a per-batch list ----------------
__global__ void __launch_bounds__(256) bandlist_k(const float* __restrict__ nac,
        const int* __restrict__ cnt, const float* __restrict__ Tarr,
        int* __restrict__ bandlist, int* __restrict__ bandcnt)
{
    int b = blockIdx.y;
    int C = min(cnt[b], CMAX);
    int p = blockIdx.x * 256 + threadIdx.x;
    if (p < C && fabsf(nac[(long)b * CMAX + p] - Tarr[b]) < BAND_EPS) {
        int slot = atomicAdd(&bandcnt[b], 1);
        if (slot < MAXBAND) bandlist[b * MAXBAND + slot] = p;
    }
}

// ---------------- fp32 recompute: 4 band rows per block, float4-packed W^T ---
__global__ void __launch_bounds__(256) bandfix_k(
    const float* __restrict__ hid, const int* __restrict__ sidx,
    const float* __restrict__ msgc,
    const float* __restrict__ w1Pf, const float* __restrict__ su_b1,
    const float* __restrict__ w2Pf, const float* __restrict__ su_b2,
    const float* __restrict__ ln_g, const float* __restrict__ ln_b,
    const float* __restrict__ auPf, const float* __restrict__ au_b1,
    const float* __restrict__ au_w2, const float* __restrict__ au_b2,
    const float* __restrict__ svals,
    const int* __restrict__ bandlist, const int* __restrict__ bandcnt,
    float* __restrict__ nac, unsigned short* __restrict__ NHb)
{
    int b = blockIdx.y;
    int M = min(bandcnt[b], MAXBAND);
    int base = blockIdx.x * 4;
    if (base >= M) return;
    int nact = min(M - base, 4);
    int tid = threadIdx.x;
    int wid = tid >> 6, lane = tid & 63;
    const float4* w1P = (const float4*)w1Pf;
    const float4* w2P = (const float4*)w2Pf;
    const float4* auP = (const float4*)auPf;
    __shared__ float xr[4][256];
    __shared__ float hy[4][256];
    __shared__ float nh[4][256];
    __shared__ float muS[4], rsS[4];
    __shared__ int ppS[4];
    if (tid < 4)
        ppS[tid] = (tid < nact) ? bandlist[b * MAXBAND + base + tid] : -1;
    __syncthreads();
    #pragma unroll
    for (int r = 0; r < 4; ++r) {
        int pp = ppS[r];
        xr[r][tid] = (pp >= 0) ? hid[((long)b * 4096 + sidx[b * 4096 + pp]) * 256 + tid] : 0.f;
    }
    __syncthreads();
    int n = tid;
    float acc[4];
    // ---- su1 ----
    #pragma unroll
    for (int r = 0; r < 4; ++r) acc[r] = 0.f;
    for (int k4 = 0; k4 < 64; ++k4) {
        float4 w = w1P[k4 * 256 + n];
        #pragma unroll
        for (int r = 0; r < 4; ++r) {
            float4 xv = *(const float4*)&xr[r][k4 * 4];
            acc[r] = fmaf(w.x, xv.x, acc[r]);
            acc[r] = fmaf(w.y, xv.y, acc[r]);
            acc[r] = fmaf(w.z, xv.z, acc[r]);
            acc[r] = fmaf(w.w, xv.w, acc[r]);
        }
    }
    float b1v = su_b1[n];
    #pragma unroll
    for (int r = 0; r < 4; ++r) {
        int pp = ppS[r];
        float s = acc[r] + b1v;
        if (pp >= 0 && pp < 256) s += msgc[((long)b * 256 + pp) * 256 + n];
        acc[r] = gelu_f(s);
    }
    __syncthreads();
    #pragma unroll
    for (int r = 0; r < 4; ++r) hy[r][n] = acc[r];
    __syncthreads();
    // ---- su2 ----
    #pragma unroll
    for (int r = 0; r < 4; ++r) acc[r] = 0.f;
    for (int k4 = 0; k4 < 64; ++k4) {
        float4 w = w2P[k4 * 256 + n];
        #pragma unroll
        for (int r = 0; r < 4; ++r) {
            float4 hv = *(const float4*)&hy[r][k4 * 4];
            acc[r] = fmaf(w.x, hv.x, acc[r]);
            acc[r] = fmaf(w.y, hv.y, acc[r]);
            acc[r] = fmaf(w.z, hv.z, acc[r]);
            acc[r] = fmaf(w.w, hv.w, acc[r]);
        }
    }
    __syncthreads();
    float b2v = su_b2[n];
    #pragma unroll
    for (int r = 0; r < 4; ++r) hy[r][n] = acc[r] + b2v;
    __syncthreads();
    // LN stats: wave wid handles row wid
    {
        int r = wid;
        float4 yv = *(const float4*)&hy[r][lane * 4];
        float s = yv.x + yv.y + yv.z + yv.w;
        float s2 = yv.x * yv.x + yv.y * yv.y + yv.z * yv.z + yv.w * yv.w;
        #pragma unroll
        for (int off = 32; off >= 1; off >>= 1) {
            s += __shfl_xor(s, off);
            s2 += __shfl_xor(s2, off);
        }
        if (lane == 0) {
            float mu = s * (1.f / 256.f);
            float var = s2 * (1.f / 256.f) - mu * mu;
            muS[r] = mu; rsS[r] = rsqrtf(var + 1e-5f);
        }
    }
    __syncthreads();
    float gv = ln_g[n], ev = ln_b[n];
    #pragma unroll
    for (int r = 0; r < 4; ++r) {
        float o = (hy[r][n] - muS[r]) * rsS[r] * gv + ev;
        nh[r][n] = o;
        if (ppS[r] >= 0) NHb[((long)b * CMAX + ppS[r]) * 256 + n] = f2bf(o);
    }
    __syncthreads();
    // ---- au ----
    #pragma unroll
    for (int r = 0; r < 4; ++r) acc[r] = 0.f;
    for (int k4 = 0; k4 < 64; ++k4) {
        float4 w = auP[k4 * 256 + n];
        #pragma unroll
        for (int r = 0; r < 4; ++r) {
            float4 xv = *(const float4*)&xr[r][k4 * 4];
            acc[r] = fmaf(w.x, xv.x, acc[r]);
            acc[r] = fmaf(w.y, xv.y, acc[r]);
            acc[r] = fmaf(w.z, xv.z, acc[r]);
            acc[r] = fmaf(w.w, xv.w, acc[r]);
        }
    }
    for (int k4 = 64; k4 < 128; ++k4) {
        float4 w = auP[k4 * 256 + n];
        #pragma unroll
        for (int r = 0; r < 4; ++r) {
            float4 hv = *(const float4*)&nh[r][(k4 - 64) * 4];
            acc[r] = fmaf(w.x, hv.x, acc[r]);
            acc[r] = fmaf(w.y, hv.y, acc[r]);
            acc[r] = fmaf(w.z, hv.z, acc[r]);
            acc[r] = fmaf(w.w, hv.w, acc[r]);
        }
    }
    float ab = au_b1[n], wv2 = au_w2[n];
    __syncthreads();
    #pragma unroll
    for (int r = 0; r < 4; ++r) hy[r][n] = gelu_f(acc[r] + ab) * wv2;
    __syncthreads();
    {
        int r = wid;
        float4 gvv = *(const float4*)&hy[r][lane * 4];
        float s = gvv.x + gvv.y + gvv.z + gvv.w;
        #pragma unroll
        for (int off = 32; off >= 1; off >>= 1) s += __shfl_xor(s, off);
        if (lane == 0 && ppS[r] >= 0) {
            float z = s + au_b2[0];
            float delta = 1.f / (1.f + expf(-z));
            float na = 0.7f * svals[b * 4096 + ppS[r]] + 0.3f * delta;
            nac[(long)b * CMAX + ppS[r]] = fminf(fmaxf(na, 0.f), 1.f);
        }
    }
}

// ---------------- scatter outputs ----------------
__global__ void __launch_bounds__(64) scatter_k(const float* __restrict__ selv,
        const int* __restrict__ selo, const int* __restrict__ selp,
        const unsigned short* __restrict__ NHb, float* __restrict__ out)
{
    int b = blockIdx.x >> 8, j = blockIdx.x & 255, t = threadIdx.x;
    int orig = selo[b * 256 + j];
    int p = selp[b * 256 + j];
    if (t == 0) out[b * 4096 + orig] = selv[b * 256 + j];
    const ushort4* src = (const ushort4*)(NHb + ((long)b * CMAX + p) * 256);
    ushort4 s = src[t];
    float4 o = make_float4(bf2f(s.x), bf2f(s.y), bf2f(s.z), bf2f(s.w));
    *(float4*)(out + 131072 + ((long)(b * 4096 + orig)) * 256 + t * 4) = o;
}

extern "C" void kernel_launch(void* const* d_in, const int* in_sizes, int n_in,
                              void* d_out, int out_size, void* d_ws, size_t ws_size,
                              hipStream_t stream)
{
    const float* act   = (const float*)d_in[0];
    const float* hid   = (const float*)d_in[1];
    const float* wi    = (const float*)d_in[2];
    const float* bi    = (const float*)d_in[3];
    const float* wo    = (const float*)d_in[4];
    const float* bo    = (const float*)d_in[5];
    const float* su_w1 = (const float*)d_in[6];
    const float* su_b1 = (const float*)d_in[7];
    const float* su_w2 = (const float*)d_in[8];
    const float* su_b2 = (const float*)d_in[9];
    const float* au_w1 = (const float*)d_in[10];
    const float* au_b1 = (const float*)d_in[11];
    const float* au_w2 = (const float*)d_in[12];
    const float* au_b2 = (const float*)d_in[13];
    const float* ln_g  = (const float*)d_in[14];
    const float* ln_b  = (const float*)d_in[15];
    float* out = (float*)d_out;

    char* ws = (char*)d_ws;
    size_t off = 0;
    auto alloc = [&](size_t bytes) {
        size_t o = off; off += (bytes + 255) & ~(size_t)255; return o;
    };
    float* svals = (float*)(ws + alloc((size_t)32 * 4096 * 4));
    int*   sidx  = (int*)  (ws + alloc((size_t)32 * 4096 * 4));
    int*   cnt   = (int*)  (ws + alloc(256));
    float* qkv   = (float*)(ws + alloc((size_t)32 * 256 * 768 * 4));
    float* Sb    = (float*)(ws + alloc((size_t)32 * 4 * 256 * 256 * 4));
    float* Ob    = (float*)(ws + alloc((size_t)32 * 256 * 256 * 4));
    float* MSG   = (float*)(ws + alloc((size_t)32 * 256 * 256 * 4));
    float* MSGC  = (float*)(ws + alloc((size_t)32 * 256 * 256 * 4));
    float* selv  = (float*)(ws + alloc((size_t)32 * 256 * 4));
    int*   selo  = (int*)  (ws + alloc((size_t)32 * 256 * 4));
    int*   selp  = (int*)  (ws + alloc((size_t)32 * 256 * 4));
    unsigned short* swb1 = (unsigned short*)(ws + alloc((size_t)256 * 512 * 2));
    unsigned short* swb2 = (unsigned short*)(ws + alloc((size_t)256 * 256 * 2));
    unsigned short* awb1 = (unsigned short*)(ws + alloc((size_t)256 * 512 * 2));
    float* w1P = (float*)(ws + alloc((size_t)256 * 256 * 4));
    float* w2P = (float*)(ws + alloc((size_t)256 * 256 * 4));
    float* auP = (float*)(ws + alloc((size_t)512 * 256 * 4));
    unsigned short* Xb   = (unsigned short*)(ws + alloc((size_t)32 * CMAX * 256 * 2));
    unsigned short* H1b  = (unsigned short*)(ws + alloc((size_t)32 * CMAX * 256 * 2));
    unsigned short* NHb  = (unsigned short*)(ws + alloc((size_t)32 * CMAX * 256 * 2));
    float* nac = (float*)(ws + alloc((size_t)32 * CMAX * 4));
    float* Tb  = (float*)(ws + alloc(128));
    int* bandl = (int*)(ws + alloc((size_t)32 * MAXBAND * 4));
    int* bandc = (int*)(ws + alloc(128));

    // 0. zero band counters
    hipMemsetAsync(bandc, 0, 32 * sizeof(int), stream);
    // 1. zero outputs
    fill0_k<<<2048, 256, 0, stream>>>((float4*)out, (long)out_size / 4);
    // 2. radix-select activations (top-256 + candidates, compacted)
    topk1_k<<<32, 256, 0, stream>>>(act, svals, sidx, cnt);
    // 3. weight conversion + packed fp32 transposes (single launch)
    prep_k<<<768, 256, 0, stream>>>(su_w1, su_w2, au_w1, swb1, swb2, awb1,
                                    w1P, w2P, auP);
    // 4. gather + bf16 candidate rows
    gatherX_k<<<dim3(CMAX / 4, 32), 256, 0, stream>>>(hid, sidx, cnt, Xb);
    // 5. qkv = gather(hidden) @ wi^T + bi
    gemm_k<64, 256, 8, 8, true, true, 1><<<dim3(3, 4, 32), 256, 0, stream>>>(
        hid, 256, (long)4096 * 256, 0, 1,
        wi, 256, 0, 0, 1,
        qkv, 768, (long)256 * 768, 0, 1,
        256, bi, nullptr, 0, sidx, 4096, 0.f);
    // 6. S = q @ k^T / 8
    gemm_k<64, 256, 8, 8, true, false, 3><<<dim3(1, 4, 128), 256, 0, stream>>>(
        qkv, 768, 196608, 64, 4,
        qkv + 256, 768, 196608, 64, 4,
        Sb, 256, 65536, 0, 1,
        64, nullptr, nullptr, 0, nullptr, 0, 0.125f);
    // 7. softmax
    softmax_k<<<8192, 256, 0, stream>>>(Sb);
    // 8. O = P @ V
    gemm_k<64, 64, 4, 4, false, false, 0><<<dim3(1, 4, 128), 256, 0, stream>>>(
        Sb, 256, 65536, 0, 1,
        qkv + 512, 768, 196608, 64, 4,
        Ob, 256, 65536, 64, 4,
        256, nullptr, nullptr, 0, nullptr, 0, 0.f);
    // 9. MSG = (O @ wo^T + bo) * topk_vals
    gemm_k<64, 256, 8, 8, true, false, 2><<<dim3(1, 4, 32), 256, 0, stream>>>(
        Ob, 256, 65536, 0, 1,
        wo, 256, 0, 0, 1,
        MSG, 256, 65536, 0, 1,
        256, bo, svals, 4096, nullptr, 0, 0.f);
    // 10. MSGC = MSG @ W1b^T
    gemm_k<64, 256, 8, 8, true, false, 0><<<dim3(1, 4, 32), 256, 0, stream>>>(
        MSG, 256, 65536, 0, 1,
        su_w1 + 256, 512, 0, 0, 1,
        MSGC, 256, 65536, 0, 1,
        256, nullptr, nullptr, 0, nullptr, 0, 0.f);
    // 11-13. candidate-row MLPs in bf16 MFMA
    dim3 mgrid(CMAX / 64, 32);
    mlp_mfma_k<1><<<mgrid, 256, 0, stream>>>(Xb, nullptr, swb1, 512, su_b1, MSGC,
        nullptr, nullptr, nullptr, nullptr, nullptr, cnt, H1b, nullptr);
    mlp_mfma_k<2><<<mgrid, 256, 0, stream>>>(H1b, nullptr, swb2, 256, su_b2, nullptr,
        ln_g, ln_b, nullptr, nullptr, nullptr, cnt, NHb, nullptr);
    mlp_mfma_k<3><<<mgrid, 256, 0, stream>>>(Xb, NHb, awb1, 512, au_b1, nullptr,
        nullptr, nullptr, au_w2, au_b2, svals, cnt, nullptr, nac);
    // 14. rank-256 value per batch (band center)
    selectT_k<<<32, 256, 0, stream>>>(nac, cnt, Tb);
    // 15a. compact band rows
    bandlist_k<<<dim3(CMAX / 256, 32), 256, 0, stream>>>(nac, cnt, Tb, bandl, bandc);
    // 15b. fp32 recompute of boundary-band rows, 4 rows/block, packed W^T
    bandfix_k<<<dim3(MAXBAND / 4, 32), 256, 0, stream>>>(hid, sidx, MSGC,
        w1P, su_b1, w2P, su_b2, ln_g, ln_b, auP, au_b1, au_w2, au_b2,
        svals, bandl, bandc, nac, NHb);
    // 16. exact top-256 selection over corrected new activations
    topk2_k<<<32, 256, 0, stream>>>(nac, sidx, cnt, selv, selo, selp);
    // 17. scatter selected rows
    scatter_k<<<8192, 64, 0, stream>>>(selv, selo, selp, NHb, out);
}